// Round 14
// baseline (189.916 us; speedup 1.0000x reference)
//
#include <hip/hip_runtime.h>
#include <math.h>

#define LSEQ 8192
#define TS   32
#define NST  8

// ---------------------------------------------------------------------------
// DPP adds: xor1 = quad_perm[1,0,3,2]=0xB1, xor2 = quad_perm[2,3,0,1]=0x4E.
// red8 = sum over 8 contiguous lanes: xor1 + xor2 (DPP) + xor4 (ds_swizzle).
// ---------------------------------------------------------------------------
template<int CTRL>
__device__ __forceinline__ float dpp_add(float x) {
  const int y = __builtin_amdgcn_update_dpp(0, __float_as_int(x), CTRL, 0xF, 0xF, true);
  return x + __int_as_float(y);
}
__device__ __forceinline__ float red8(float x) {
  x = dpp_add<0xB1>(x);
  x = dpp_add<0x4E>(x);
  x += __int_as_float(__builtin_amdgcn_ds_swizzle(__float_as_int(x), 0x101F));
  return x;
}

// ---------------------------------------------------------------------------
// K0: weight re-layouts (run once, tiny):
//  xwT [dir][k=192][48]   (x_proj transposed, r-padded to 48 with zeros)
//  inwT[k=96][e=384]      (in_proj transposed)
//  owT [k=192][e=96]      (out_proj transposed)
// ---------------------------------------------------------------------------
__global__ __launch_bounds__(256) void k0_wt(const float* __restrict__ xw_f,
    const float* __restrict__ xw_b, const float* __restrict__ in_w,
    const float* __restrict__ ow, float* __restrict__ xwT,
    float* __restrict__ inwT, float* __restrict__ owT) {
  const int step = gridDim.x * 256;
  const int t0 = blockIdx.x * 256 + threadIdx.x;
  for (int idx = t0; idx < 2 * 192 * 48; idx += step) {
    const int dir = idx / (192 * 48), rem = idx - dir * 192 * 48;
    const int k = rem / 48, r = rem - k * 48;
    const float* w = dir ? xw_b : xw_f;
    xwT[idx] = (r < 38) ? w[r * 192 + k] : 0.f;
  }
  for (int idx = t0; idx < 96 * 384; idx += step) {
    const int k = idx / 384, e = idx - k * 384;
    inwT[idx] = in_w[e * 96 + k];
  }
  for (int idx = t0; idx < 192 * 96; idx += step) {
    const int k = idx / 96, e = idx - k * 96;
    owT[idx] = ow[e * 192 + k];
  }
}

// ---------------------------------------------------------------------------
// K1: serpentine gather + LayerNorm over C=96.  out: xnT[c][b*8192 + l]
// ---------------------------------------------------------------------------
__global__ __launch_bounds__(256) void k1_serp_ln(const float* __restrict__ x,
    const float* __restrict__ gam, const float* __restrict__ bet,
    float* __restrict__ xnT) {
  const int b  = blockIdx.x >> 7;
  const int l0 = (blockIdx.x & 127) << 6;
  __shared__ float xs[96][65];
  __shared__ float mu[64], rs[64];
  const int tid = threadIdx.x;
  for (int idx = tid; idx < 96 * 64; idx += 256) {
    const int c = idx >> 6, l = idx & 63;
    const int lg = l0 + l;
    const int hh = (lg >> 5) & 31, w = lg & 31;
    const int lsrc = (hh & 1) ? (lg + 31 - 2 * w) : lg;
    xs[c][l] = x[(b * 96 + c) * LSEQ + lsrc];
  }
  __syncthreads();
  {
    const int l = tid >> 2, k = tid & 3;
    float s = 0.f, s2 = 0.f;
    for (int c = k; c < 96; c += 4) { const float v = xs[c][l]; s += v; s2 += v * v; }
    s  += __shfl_xor(s, 1);  s  += __shfl_xor(s, 2);
    s2 += __shfl_xor(s2, 1); s2 += __shfl_xor(s2, 2);
    if (k == 0) {
      const float m = s * (1.f / 96.f);
      const float var = s2 * (1.f / 96.f) - m * m;
      mu[l] = m; rs[l] = rsqrtf(var + 1e-5f);
    }
  }
  __syncthreads();
  for (int idx = tid; idx < 96 * 64; idx += 256) {
    const int c = idx >> 6, l = idx & 63;
    xnT[c * 16384 + (b << 13) + l0 + l] =
        (xs[c][l] - mu[l]) * rs[l] * gam[c] + bet[c];
  }
}

// ---------------------------------------------------------------------------
// K2: in_proj GEMM — LDS tiles padded to 68 (16B-aligned rows -> b128 reads).
// ---------------------------------------------------------------------------
__global__ __launch_bounds__(256) void k2_inproj(const float* __restrict__ xnT,
    const float* __restrict__ inwT, float* __restrict__ xz) {
  const int m0 = blockIdx.x << 6;
  const int e0 = blockIdx.y << 6;
  __shared__ float As[96][68];
  __shared__ float Ws[96][68];
  const int tid = threadIdx.x;
  for (int idx = tid; idx < 96 * 64; idx += 256) {
    const int k = idx >> 6, r = idx & 63;
    As[k][r] = xnT[(size_t)k * 16384 + m0 + r];
    Ws[k][r] = inwT[k * 384 + e0 + r];
  }
  __syncthreads();
  const int tx = tid & 15, ty = tid >> 4;
  const int la = tx << 2, ea = ty << 2;
  float acc[4][4] = {};
  for (int k = 0; k < 96; ++k) {
    const float4 av = *(const float4*)&As[k][la];
    const float4 bv = *(const float4*)&Ws[k][ea];
    acc[0][0] = fmaf(bv.x, av.x, acc[0][0]); acc[0][1] = fmaf(bv.x, av.y, acc[0][1]);
    acc[0][2] = fmaf(bv.x, av.z, acc[0][2]); acc[0][3] = fmaf(bv.x, av.w, acc[0][3]);
    acc[1][0] = fmaf(bv.y, av.x, acc[1][0]); acc[1][1] = fmaf(bv.y, av.y, acc[1][1]);
    acc[1][2] = fmaf(bv.y, av.z, acc[1][2]); acc[1][3] = fmaf(bv.y, av.w, acc[1][3]);
    acc[2][0] = fmaf(bv.z, av.x, acc[2][0]); acc[2][1] = fmaf(bv.z, av.y, acc[2][1]);
    acc[2][2] = fmaf(bv.z, av.z, acc[2][2]); acc[2][3] = fmaf(bv.z, av.w, acc[2][3]);
    acc[3][0] = fmaf(bv.w, av.x, acc[3][0]); acc[3][1] = fmaf(bv.w, av.y, acc[3][1]);
    acc[3][2] = fmaf(bv.w, av.z, acc[3][2]); acc[3][3] = fmaf(bv.w, av.w, acc[3][3]);
  }
  const int b = m0 >> 13, l0 = m0 & (LSEQ - 1);
  const bool dos = (e0 >= 192);
#pragma unroll
  for (int j = 0; j < 4; ++j) {
    const int e = e0 + ea + j;
    float4 v;
    v.x = acc[j][0]; v.y = acc[j][1]; v.z = acc[j][2]; v.w = acc[j][3];
    if (dos) {
      v.x = v.x / (1.f + __expf(-v.x)); v.y = v.y / (1.f + __expf(-v.y));
      v.z = v.z / (1.f + __expf(-v.z)); v.w = v.w / (1.f + __expf(-v.w));
    }
    *(float4*)(&xz[((size_t)b * 384 + e) * LSEQ + l0 + la]) = v;
  }
}

// ---------------------------------------------------------------------------
// K3a: depthwise conv + silu for BOTH directions (shared xz read).
// ---------------------------------------------------------------------------
__global__ __launch_bounds__(256) void k3a_conv(const float* __restrict__ xz,
    const float* __restrict__ cw_f, const float* __restrict__ cb_f,
    const float* __restrict__ cw_b, const float* __restrict__ cb_b,
    float* __restrict__ xc) {
  const int l = (blockIdx.x << 8) + threadIdx.x;
  const int d = blockIdx.y, b = blockIdx.z;
  const float* xin = xz + ((size_t)b * 384 + d) * LSEQ;
  float xv[7];
#pragma unroll
  for (int j = -3; j <= 3; ++j) {
    const int ls = l + j;
    xv[j + 3] = ((unsigned)ls < LSEQ) ? xin[ls] : 0.f;
  }
  float af = cb_f[d], ab = cb_b[d];
#pragma unroll
  for (int j = 0; j < 4; ++j) {
    af = fmaf(cw_f[d * 4 + j], xv[j], af);
    ab = fmaf(cw_b[d * 4 + j], xv[6 - j], ab);
  }
  xc[((size_t)(b)       * 192 + d) * LSEQ + l] = af / (1.f + __expf(-af));
  xc[((size_t)(2 + b)   * 192 + d) * LSEQ + l] = ab / (1.f + __expf(-ab));
}

// ---------------------------------------------------------------------------
// K3b: x_proj + dt_proj + softplus, rewritten as an LDS-tile GEMM
// (R12 lesson: the stall was the wave-uniform weight s_load chain —
// SMEM+LDS share lgkmcnt so every k-step serialized at L2 latency.
// Both operands now live in LDS; ds_reads pipeline.)
// out[r=0..40][l=64] per block; thread = (16 lx x 4l) x (16 ry x 3r).
// Results go to outs[40][68] LDS; BC extraction + dt phase read from there;
// dtw staged in LDS too (kills the dt-phase s_load chain).
// ---------------------------------------------------------------------------
__global__ __launch_bounds__(256, 2) void k3b_xproj(const float* __restrict__ xc,
    const float* __restrict__ xwT,
    const float* __restrict__ dtw_f, const float* __restrict__ dtb_f,
    const float* __restrict__ dtw_b, const float* __restrict__ dtb_b,
    float* __restrict__ dt, float* __restrict__ Bo, float* __restrict__ Co) {
  __shared__ float As[48][68];
  __shared__ float Wc[48][48];
  __shared__ float outs[40][68];
  __shared__ float dtwl[1152];
  const int dirb = blockIdx.y, dir = dirb >> 1;
  const int tid = threadIdx.x;
  const int lane = tid & 63, w = tid >> 6;
  const int l0 = blockIdx.x << 6;
  const float* pcBase = xc + (size_t)dirb * 192 * LSEQ + l0;
  const float* wt = xwT + dir * 192 * 48;
  const float* dtwp = dir ? dtw_b : dtw_f;
  for (int idx = tid; idx < 1152; idx += 256) dtwl[idx] = dtwp[idx];
  const int tx = tid & 15, ty = tid >> 4;
  const int la = tx << 2, ra = ty * 3;
  float acc[3][4] = {};
  for (int kc = 0; kc < 192; kc += 48) {
    if (kc) __syncthreads();
    for (int idx = tid; idx < 48 * 64; idx += 256) {
      const int k = idx >> 6, cc = idx & 63;
      As[k][cc] = pcBase[(size_t)(kc + k) * LSEQ + cc];
    }
    for (int idx = tid; idx < 48 * 48; idx += 256) {
      const int k = idx / 48, r = idx - k * 48;
      Wc[k][r] = wt[(kc + k) * 48 + r];
    }
    __syncthreads();
#pragma unroll 4
    for (int k = 0; k < 48; ++k) {
      const float4 a4 = *(const float4*)&As[k][la];
      const float w0 = Wc[k][ra], w1 = Wc[k][ra + 1], w2 = Wc[k][ra + 2];
      acc[0][0] = fmaf(w0, a4.x, acc[0][0]); acc[0][1] = fmaf(w0, a4.y, acc[0][1]);
      acc[0][2] = fmaf(w0, a4.z, acc[0][2]); acc[0][3] = fmaf(w0, a4.w, acc[0][3]);
      acc[1][0] = fmaf(w1, a4.x, acc[1][0]); acc[1][1] = fmaf(w1, a4.y, acc[1][1]);
      acc[1][2] = fmaf(w1, a4.z, acc[1][2]); acc[1][3] = fmaf(w1, a4.w, acc[1][3]);
      acc[2][0] = fmaf(w2, a4.x, acc[2][0]); acc[2][1] = fmaf(w2, a4.y, acc[2][1]);
      acc[2][2] = fmaf(w2, a4.z, acc[2][2]); acc[2][3] = fmaf(w2, a4.w, acc[2][3]);
    }
  }
  __syncthreads();
#pragma unroll
  for (int j = 0; j < 3; ++j) {
    const int r = ra + j;
    if (r < 40) {
#pragma unroll
      for (int i = 0; i < 4; ++i) outs[r][la + i] = acc[j][i];
    }
  }
  __syncthreads();
  // --- BC extraction (coalesced float4 writes)
  {
    const int lq = tid >> 2, g = tid & 3;
    float vB[4], vC[4];
#pragma unroll
    for (int i = 0; i < 4; ++i) {
      vB[i] = outs[6 + 4 * g + i][lq];
      vC[i] = outs[22 + 4 * g + i][lq];
    }
    const size_t off = ((size_t)dirb * LSEQ + l0 + lq) * 16 + 4 * g;
    *(float4*)&Bo[off] = make_float4(vB[0], vB[1], vB[2], vB[3]);
    *(float4*)&Co[off] = make_float4(vC[0], vC[1], vC[2], vC[3]);
  }
  // --- dt_proj + softplus (weights from LDS; no s_load chain)
  const float* db = dir ? dtb_b : dtb_f;
  const float v0 = outs[0][lane], v1 = outs[1][lane], v2 = outs[2][lane],
              v3 = outs[3][lane], v4 = outs[4][lane], v5 = outs[5][lane];
  float* pdt = dt + (size_t)dirb * 192 * LSEQ + l0 + lane;
#pragma unroll 2
  for (int i = 0; i < 48; ++i) {
    const int d = w * 48 + i;
    float s = db[d];
    s = fmaf(dtwl[d * 6 + 0], v0, s);
    s = fmaf(dtwl[d * 6 + 1], v1, s);
    s = fmaf(dtwl[d * 6 + 2], v2, s);
    s = fmaf(dtwl[d * 6 + 3], v3, s);
    s = fmaf(dtwl[d * 6 + 4], v4, s);
    s = fmaf(dtwl[d * 6 + 5], v5, s);
    pdt[(size_t)d * LSEQ] = (s > 20.f) ? s : __logf(1.f + __expf(s));
  }
}

// ---------------------------------------------------------------------------
// Scan pass A — 2 states per lane: 8 lanes per d, 32 d-rows per block.
// ---------------------------------------------------------------------------
template<int DIR>
__device__ __forceinline__ void scanA_body(
    float2 (*sdt)[32][34], float (*sb)[TS][16],
    const float* __restrict__ dtg, const float* __restrict__ xcg,
    const float* __restrict__ pB, const float* __restrict__ Al,
    float* __restrict__ Pb, float* __restrict__ Hb, int b, int c, int dg) {
  const int tid = threadIdx.x;
  const int dl = tid >> 3, n = tid & 7;
  const int dirb = DIR * 2 + b;
  const int d = (dg << 5) + dl;
  const float Adn1 = -__expf(Al[d * 16 + n]);
  const float Adn2 = -__expf(Al[d * 16 + n + 8]);
  const size_t rowbase = ((size_t)(dirb * 192) + (dg << 5)) * LSEQ;
  const float* dtp = dtg + rowbase;
  const float* xcp = xcg + rowbase;
  const int c0 = c << 8;
  const int sr0 = tid >> 4, spr = (tid & 15) * 2, sr1 = sr0 + 16;
  const int wt = tid >> 2, wf = (tid & 3) * 4;
  {
    const int tc = c0 + (DIR ? (NST - 1) : 0) * TS;
    const float2 a0 = *(const float2*)&dtp[(size_t)sr0 * LSEQ + tc + spr];
    const float2 x0 = *(const float2*)&xcp[(size_t)sr0 * LSEQ + tc + spr];
    const float2 a1 = *(const float2*)&dtp[(size_t)sr1 * LSEQ + tc + spr];
    const float2 x1 = *(const float2*)&xcp[(size_t)sr1 * LSEQ + tc + spr];
    float4 k0; k0.x = a0.x; k0.y = a0.x * x0.x; k0.z = a0.y; k0.w = a0.y * x0.y;
    float4 k1; k1.x = a1.x; k1.y = a1.x * x1.x; k1.z = a1.y; k1.w = a1.y * x1.y;
    *(float4*)&sdt[0][sr0][spr] = k0;
    *(float4*)&sdt[0][sr1][spr] = k1;
    if (tid < 128) {
      const float4 bv = *(const float4*)&pB[(size_t)(tc + wt) * 16 + wf];
      *(float4*)&sb[0][wt][wf] = bv;
    }
  }
  __syncthreads();
  float h1 = 0.f, h2 = 0.f, dts = 0.f;
  int buf = 0;
  for (int i = 0; i < NST; ++i) {
    const int s = DIR ? (NST - 1 - i) : i;
    float2 a0 = make_float2(0.f, 0.f), x0 = a0, a1 = a0, x1 = a0;
    float4 bv = make_float4(0.f, 0.f, 0.f, 0.f);
    if (i + 1 < NST) {
      const int tn = c0 + (DIR ? (s - 1) : (s + 1)) * TS;
      a0 = *(const float2*)&dtp[(size_t)sr0 * LSEQ + tn + spr];
      x0 = *(const float2*)&xcp[(size_t)sr0 * LSEQ + tn + spr];
      a1 = *(const float2*)&dtp[(size_t)sr1 * LSEQ + tn + spr];
      x1 = *(const float2*)&xcp[(size_t)sr1 * LSEQ + tn + spr];
      if (tid < 128) bv = *(const float4*)&pB[(size_t)(tn + wt) * 16 + wf];
    }
#pragma unroll
    for (int tt = 0; tt < TS; ++tt) {
      const int t = DIR ? (TS - 1 - tt) : tt;
      const float2 xv = sdt[buf][dl][t];
      const float B1 = sb[buf][t][n];
      const float B2 = sb[buf][t][n + 8];
      const float e1 = __expf(xv.x * Adn1);
      const float e2 = __expf(xv.x * Adn2);
      h1 = fmaf(e1, h1, xv.y * B1);
      h2 = fmaf(e2, h2, xv.y * B2);
      dts += xv.x;
    }
    if (i + 1 < NST) {
      float4 k0; k0.x = a0.x; k0.y = a0.x * x0.x; k0.z = a0.y; k0.w = a0.y * x0.y;
      float4 k1; k1.x = a1.x; k1.y = a1.x * x1.x; k1.z = a1.y; k1.w = a1.y * x1.y;
      *(float4*)&sdt[buf ^ 1][sr0][spr] = k0;
      *(float4*)&sdt[buf ^ 1][sr1][spr] = k1;
      if (tid < 128) *(float4*)&sb[buf ^ 1][wt][wf] = bv;
    }
    __syncthreads();
    buf ^= 1;
  }
  const int o = ((dirb * 32 + c) * 192 + d) * 16 + n;
  Pb[o]     = __expf(dts * Adn1);
  Pb[o + 8] = __expf(dts * Adn2);
  Hb[o]     = h1;
  Hb[o + 8] = h2;
}

__global__ __launch_bounds__(256) void k4_scanA(const float* __restrict__ dtg,
    const float* __restrict__ xcg, const float* __restrict__ Bo,
    const float* __restrict__ Al_f, const float* __restrict__ Al_b,
    float* __restrict__ Pb, float* __restrict__ Hb) {
  __shared__ float2 sdt[2][32][34];
  __shared__ float sb[2][TS][16];
  const int b = blockIdx.y, c = blockIdx.x & 31, dg = blockIdx.x >> 5;
  const float* pB0 = Bo + (size_t)(0 * 2 + b) * LSEQ * 16;
  const float* pB1 = Bo + (size_t)(1 * 2 + b) * LSEQ * 16;
  if (blockIdx.z == 0) scanA_body<0>(sdt, sb, dtg, xcg, pB0, Al_f, Pb, Hb, b, c, dg);
  else                 scanA_body<1>(sdt, sb, dtg, xcg, pB1, Al_b, Pb, Hb, b, c, dg);
}

// ---------------------------------------------------------------------------
// K5: chunk-level prefix over 32 chunks
// ---------------------------------------------------------------------------
__global__ __launch_bounds__(256) void k5_scanB(const float* __restrict__ Pb,
    const float* __restrict__ Hb, float* __restrict__ H0) {
  const int g = blockIdx.x * 256 + threadIdx.x;
  const int dirb = g / 3072, dn = g - dirb * 3072;
  const int dir = dirb >> 1;
  const int base = dirb * (32 * 3072) + dn;
  float h = 0.f;
  if (dir == 0) {
    for (int c = 0; c < 32; ++c) {
      const int o = base + c * 3072;
      H0[o] = h;
      h = fmaf(Pb[o], h, Hb[o]);
    }
  } else {
    for (int c = 31; c >= 0; --c) {
      const int o = base + c * 3072;
      H0[o] = h;
      h = fmaf(Pb[o], h, Hb[o]);
    }
  }
}

// ---------------------------------------------------------------------------
// Scan pass C — 2 states per lane: 8 lanes per d, red8, 32 d-rows per block.
// ---------------------------------------------------------------------------
template<int DIR>
__device__ __forceinline__ void scanC_body(
    float2 (*sdt)[32][34], float2 (*sbc)[TS][16],
    const float* __restrict__ dtg, const float* __restrict__ xcg,
    const float* __restrict__ pB, const float* __restrict__ pC,
    const float* __restrict__ xz,
    const float* __restrict__ Al, const float* __restrict__ Dv_,
    const float* __restrict__ H0, float* __restrict__ yout,
    int b, int c, int dg) {
  const int tid = threadIdx.x;
  const int dl = tid >> 3, n = tid & 7;
  const int dirb = DIR * 2 + b;
  const int d = (dg << 5) + dl;
  const float Adn1 = -__expf(Al[d * 16 + n]);
  const float Adn2 = -__expf(Al[d * 16 + n + 8]);
  const float Dv = Dv_[d];
  const size_t rowbase = ((size_t)(dirb * 192) + (dg << 5)) * LSEQ;
  const float* dtp = dtg + rowbase;
  const float* xcp = xcg + rowbase;
  const float* xcq = xcg + ((size_t)(dirb * 192) + d) * LSEQ;
  const float* psp = xz + ((size_t)(b * 384) + 192 + d) * LSEQ;
  float* py = yout + ((size_t)(b * 192) + d) * LSEQ;
  const int o = ((dirb * 32 + c) * 192 + d) * 16 + n;
  float h1 = H0[o], h2 = H0[o + 8];
  const int c0 = c << 8;
  const int sr0 = tid >> 4, spr = (tid & 15) * 2, sr1 = sr0 + 16;
  const int sbt = tid >> 3, sbp = (tid & 7) * 2;
  float cx0, cx1, cx2, cx3, sp0, sp1, sp2, sp3;
  {
    const int tc = c0 + (DIR ? (NST - 1) : 0) * TS;
    const float2 a0 = *(const float2*)&dtp[(size_t)sr0 * LSEQ + tc + spr];
    const float2 x0 = *(const float2*)&xcp[(size_t)sr0 * LSEQ + tc + spr];
    const float2 a1 = *(const float2*)&dtp[(size_t)sr1 * LSEQ + tc + spr];
    const float2 x1 = *(const float2*)&xcp[(size_t)sr1 * LSEQ + tc + spr];
    const float2 b2 = *(const float2*)&pB[(size_t)(tc + sbt) * 16 + sbp];
    const float2 c2 = *(const float2*)&pC[(size_t)(tc + sbt) * 16 + sbp];
    float4 k0; k0.x = a0.x; k0.y = a0.x * x0.x; k0.z = a0.y; k0.w = a0.y * x0.y;
    float4 k1; k1.x = a1.x; k1.y = a1.x * x1.x; k1.z = a1.y; k1.w = a1.y * x1.y;
    *(float4*)&sdt[0][sr0][spr] = k0;
    *(float4*)&sdt[0][sr1][spr] = k1;
    *(float4*)&sbc[0][sbt][sbp] = make_float4(b2.x, c2.x, b2.y, c2.y);
    cx0 = xcq[tc + n];      cx1 = xcq[tc + 8 + n];
    cx2 = xcq[tc + 16 + n]; cx3 = xcq[tc + 24 + n];
    sp0 = psp[tc + n];      sp1 = psp[tc + 8 + n];
    sp2 = psp[tc + 16 + n]; sp3 = psp[tc + 24 + n];
  }
  __syncthreads();
  int buf = 0;
  for (int i = 0; i < NST; ++i) {
    const int s = DIR ? (NST - 1 - i) : i;
    const int t0 = c0 + s * TS;
    float2 a0 = make_float2(0.f, 0.f), x0 = a0, a1 = a0, x1 = a0, b2 = a0, c2 = a0;
    float nx0 = 0.f, nx1 = 0.f, nx2 = 0.f, nx3 = 0.f;
    float ns0 = 0.f, ns1 = 0.f, ns2 = 0.f, ns3 = 0.f;
    if (i + 1 < NST) {
      const int tn = c0 + (DIR ? (s - 1) : (s + 1)) * TS;
      a0 = *(const float2*)&dtp[(size_t)sr0 * LSEQ + tn + spr];
      x0 = *(const float2*)&xcp[(size_t)sr0 * LSEQ + tn + spr];
      a1 = *(const float2*)&dtp[(size_t)sr1 * LSEQ + tn + spr];
      x1 = *(const float2*)&xcp[(size_t)sr1 * LSEQ + tn + spr];
      b2 = *(const float2*)&pB[(size_t)(tn + sbt) * 16 + sbp];
      c2 = *(const float2*)&pC[(size_t)(tn + sbt) * 16 + sbp];
      nx0 = xcq[tn + n];      nx1 = xcq[tn + 8 + n];
      nx2 = xcq[tn + 16 + n]; nx3 = xcq[tn + 24 + n];
      ns0 = psp[tn + n];      ns1 = psp[tn + 8 + n];
      ns2 = psp[tn + 16 + n]; ns3 = psp[tn + 24 + n];
    }
    float pq0 = 0.f, pq1 = 0.f, pq2 = 0.f, pq3 = 0.f;
#pragma unroll
    for (int tt = 0; tt < TS; ++tt) {
      const int t = DIR ? (TS - 1 - tt) : tt;
      const float2 xv = sdt[buf][dl][t];
      const float2 v1 = sbc[buf][t][n];
      const float2 v2 = sbc[buf][t][n + 8];
      const float e1 = __expf(xv.x * Adn1);
      const float e2 = __expf(xv.x * Adn2);
      h1 = fmaf(e1, h1, xv.y * v1.x);
      h2 = fmaf(e2, h2, xv.y * v2.x);
      float p = fmaf(h2, v2.y, h1 * v1.y);
      p = red8(p);
      const bool m = ((t & 7) == n);
      if ((t >> 3) == 0)      pq0 = m ? p : pq0;
      else if ((t >> 3) == 1) pq1 = m ? p : pq1;
      else if ((t >> 3) == 2) pq2 = m ? p : pq2;
      else                    pq3 = m ? p : pq3;
    }
    py[t0 + n]      = fmaf(Dv, cx0, pq0) * sp0;
    py[t0 + 8 + n]  = fmaf(Dv, cx1, pq1) * sp1;
    py[t0 + 16 + n] = fmaf(Dv, cx2, pq2) * sp2;
    py[t0 + 24 + n] = fmaf(Dv, cx3, pq3) * sp3;
    if (i + 1 < NST) {
      float4 k0; k0.x = a0.x; k0.y = a0.x * x0.x; k0.z = a0.y; k0.w = a0.y * x0.y;
      float4 k1; k1.x = a1.x; k1.y = a1.x * x1.x; k1.z = a1.y; k1.w = a1.y * x1.y;
      *(float4*)&sdt[buf ^ 1][sr0][spr] = k0;
      *(float4*)&sdt[buf ^ 1][sr1][spr] = k1;
      *(float4*)&sbc[buf ^ 1][sbt][sbp] = make_float4(b2.x, c2.x, b2.y, c2.y);
      cx0 = nx0; cx1 = nx1; cx2 = nx2; cx3 = nx3;
      sp0 = ns0; sp1 = ns1; sp2 = ns2; sp3 = ns3;
    }
    __syncthreads();
    buf ^= 1;
  }
}

__global__ __launch_bounds__(256) void k6_scanC(const float* __restrict__ dtg,
    const float* __restrict__ xcg, const float* __restrict__ Bo,
    const float* __restrict__ Co, const float* __restrict__ xz,
    const float* __restrict__ Al_f, const float* __restrict__ Al_b,
    const float* __restrict__ D_f, const float* __restrict__ D_b,
    const float* __restrict__ H0,
    float* __restrict__ yf, float* __restrict__ yb) {
  __shared__ float2 sdt[2][32][34];
  __shared__ float2 sbc[2][TS][16];
  const int b = blockIdx.y, c = blockIdx.x & 31, dg = blockIdx.x >> 5;
  const float* pB0 = Bo + (size_t)(0 * 2 + b) * LSEQ * 16;
  const float* pB1 = Bo + (size_t)(1 * 2 + b) * LSEQ * 16;
  const float* pC0 = Co + (size_t)(0 * 2 + b) * LSEQ * 16;
  const float* pC1 = Co + (size_t)(1 * 2 + b) * LSEQ * 16;
  if (blockIdx.z == 0)
    scanC_body<0>(sdt, sbc, dtg, xcg, pB0, pC0, xz, Al_f, D_f, H0, yf, b, c, dg);
  else
    scanC_body<1>(sdt, sbc, dtg, xcg, pB1, pC1, xz, Al_b, D_b, H0, yb, b, c, dg);
}

// ---------------------------------------------------------------------------
// K7: out_proj GEMM — LDS-tile structure, As padded to 68 (b128 reads).
// ---------------------------------------------------------------------------
__global__ __launch_bounds__(256) void k7_outproj(const float* __restrict__ yf,
    const float* __restrict__ yb, const float* __restrict__ owT,
    float* __restrict__ out) {
  const int m0 = blockIdx.x << 6;
  const int e0 = blockIdx.y * 48;
  const int b = m0 >> 13, l0 = m0 & (LSEQ - 1);
  __shared__ float As[48][68];
  __shared__ float Ws[48][49];
  const int tid = threadIdx.x;
  const int tx = tid & 15, ty = tid >> 4;
  const int la = tx << 2, ea = ty * 3;
  float acc[3][4] = {};
  for (int kc = 0; kc < 192; kc += 48) {
    for (int idx = tid; idx < 48 * 64; idx += 256) {
      const int k = idx >> 6, l = idx & 63;
      const size_t off = ((size_t)b * 192 + kc + k) * LSEQ + l0 + l;
      As[k][l] = yf[off] + yb[off];
    }
    for (int idx = tid; idx < 48 * 48; idx += 256) {
      const int k = idx / 48, e = idx - k * 48;
      Ws[k][e] = owT[(kc + k) * 96 + e0 + e];
    }
    __syncthreads();
#pragma unroll 4
    for (int k = 0; k < 48; ++k) {
      const float4 a4 = *(const float4*)&As[k][la];
      const float w0 = Ws[k][ea], w1 = Ws[k][ea + 1], w2 = Ws[k][ea + 2];
      acc[0][0] = fmaf(w0, a4.x, acc[0][0]); acc[0][1] = fmaf(w0, a4.y, acc[0][1]);
      acc[0][2] = fmaf(w0, a4.z, acc[0][2]); acc[0][3] = fmaf(w0, a4.w, acc[0][3]);
      acc[1][0] = fmaf(w1, a4.x, acc[1][0]); acc[1][1] = fmaf(w1, a4.y, acc[1][1]);
      acc[1][2] = fmaf(w1, a4.z, acc[1][2]); acc[1][3] = fmaf(w1, a4.w, acc[1][3]);
      acc[2][0] = fmaf(w2, a4.x, acc[2][0]); acc[2][1] = fmaf(w2, a4.y, acc[2][1]);
      acc[2][2] = fmaf(w2, a4.z, acc[2][2]); acc[2][3] = fmaf(w2, a4.w, acc[2][3]);
    }
    __syncthreads();
  }
#pragma unroll
  for (int j = 0; j < 3; ++j) {
    const int e = e0 + ea + j;
#pragma unroll
    for (int i = 0; i < 4; ++i) {
      const int l = l0 + la + i;
      const int hh = (l >> 5) & 31, ww = l & 31;
      const int lp = (hh & 1) ? (l + 31 - 2 * ww) : l;
      out[((size_t)b * 96 + e) * LSEQ + lp] = acc[j][i];
    }
  }
}

// ---------------------------------------------------------------------------
extern "C" void kernel_launch(void* const* d_in, const int* in_sizes, int n_in,
                              void* d_out, int out_size, void* d_ws, size_t ws_size,
                              hipStream_t stream) {
  const float* x     = (const float*)d_in[0];
  const float* ln_g  = (const float*)d_in[1];
  const float* ln_b  = (const float*)d_in[2];
  const float* in_w  = (const float*)d_in[3];
  const float* cw_f  = (const float*)d_in[4];
  const float* cb_f  = (const float*)d_in[5];
  const float* xw_f  = (const float*)d_in[6];
  const float* dtw_f = (const float*)d_in[7];
  const float* dtb_f = (const float*)d_in[8];
  const float* Al_f  = (const float*)d_in[9];
  const float* D_f   = (const float*)d_in[10];
  const float* cw_b  = (const float*)d_in[11];
  const float* cb_b  = (const float*)d_in[12];
  const float* xw_b  = (const float*)d_in[13];
  const float* dtw_b = (const float*)d_in[14];
  const float* dtb_b = (const float*)d_in[15];
  const float* Al_b  = (const float*)d_in[16];
  const float* D_b   = (const float*)d_in[17];
  const float* ow    = (const float*)d_in[18];
  float* out = (float*)d_out;

  float* ws = (float*)d_ws;
  float* xnT  = ws; ws += (size_t)16384 * 96;
  float* xz   = ws; ws += (size_t)2 * 384 * LSEQ;
  float* xc   = ws; ws += (size_t)4 * 192 * LSEQ;
  float* dt   = ws; ws += (size_t)4 * 192 * LSEQ;
  float* Bo   = ws; ws += (size_t)4 * LSEQ * 16;
  float* Co   = ws; ws += (size_t)4 * LSEQ * 16;
  float* yf   = ws; ws += (size_t)2 * 192 * LSEQ;
  float* yb   = ws; ws += (size_t)2 * 192 * LSEQ;
  float* Pb   = ws; ws += (size_t)4 * 32 * 192 * 16;
  float* Hb   = ws; ws += (size_t)4 * 32 * 192 * 16;
  float* H0   = ws; ws += (size_t)4 * 32 * 192 * 16;
  float* xwT  = ws; ws += (size_t)2 * 192 * 48;
  float* inwT = ws; ws += (size_t)96 * 384;
  float* owT  = ws; ws += (size_t)192 * 96;

  k0_wt<<<dim3(64), dim3(256), 0, stream>>>(xw_f, xw_b, in_w, ow, xwT, inwT, owT);
  k1_serp_ln<<<dim3(256), dim3(256), 0, stream>>>(x, ln_g, ln_b, xnT);
  k2_inproj<<<dim3(256, 6), dim3(256), 0, stream>>>(xnT, inwT, xz);
  k3a_conv<<<dim3(32, 192, 2), dim3(256), 0, stream>>>(xz, cw_f, cb_f, cw_b, cb_b, xc);
  k3b_xproj<<<dim3(128, 4), dim3(256), 0, stream>>>(xc, xwT,
      dtw_f, dtb_f, dtw_b, dtb_b, dt, Bo, Co);
  k4_scanA<<<dim3(192, 2, 2), dim3(256), 0, stream>>>(dt, xc, Bo,
      Al_f, Al_b, Pb, Hb);
  k5_scanB<<<dim3(48), dim3(256), 0, stream>>>(Pb, Hb, H0);
  k6_scanC<<<dim3(192, 2, 2), dim3(256), 0, stream>>>(dt, xc, Bo, Co,
      xz, Al_f, Al_b, D_f, D_b, H0, yf, yb);
  k7_outproj<<<dim3(256, 2), dim3(256), 0, stream>>>(yf, yb, owT, out);
}

// Round 15
// 178.373 us; speedup vs baseline: 1.0647x; 1.0647x over previous
//
#include <hip/hip_runtime.h>
#include <math.h>

#define LSEQ 8192
#define TS   32
#define NST  8

// ---------------------------------------------------------------------------
// DPP adds + red8 (sum over 8 contiguous lanes).
// ---------------------------------------------------------------------------
template<int CTRL>
__device__ __forceinline__ float dpp_add(float x) {
  const int y = __builtin_amdgcn_update_dpp(0, __float_as_int(x), CTRL, 0xF, 0xF, true);
  return x + __int_as_float(y);
}
__device__ __forceinline__ float red8(float x) {
  x = dpp_add<0xB1>(x);
  x = dpp_add<0x4E>(x);
  x += __int_as_float(__builtin_amdgcn_ds_swizzle(__float_as_int(x), 0x101F));
  return x;
}

// ---------------------------------------------------------------------------
// K0: weight re-layouts:
//  xwT [dir][k=192][64]   (x_proj transposed, r-padded to 64 with zeros)
//  inwT[k=96][e=384]      (in_proj transposed)
//  owT [k=192][e=96]      (out_proj transposed)
// ---------------------------------------------------------------------------
__global__ __launch_bounds__(256) void k0_wt(const float* __restrict__ xw_f,
    const float* __restrict__ xw_b, const float* __restrict__ in_w,
    const float* __restrict__ ow, float* __restrict__ xwT,
    float* __restrict__ inwT, float* __restrict__ owT) {
  const int step = gridDim.x * 256;
  const int t0 = blockIdx.x * 256 + threadIdx.x;
  for (int idx = t0; idx < 2 * 192 * 64; idx += step) {
    const int dir = idx / (192 * 64), rem = idx - dir * 192 * 64;
    const int k = rem >> 6, r = rem & 63;
    const float* w = dir ? xw_b : xw_f;
    xwT[idx] = (r < 38) ? w[r * 192 + k] : 0.f;
  }
  for (int idx = t0; idx < 96 * 384; idx += step) {
    const int k = idx / 384, e = idx - k * 384;
    inwT[idx] = in_w[e * 96 + k];
  }
  for (int idx = t0; idx < 192 * 96; idx += step) {
    const int k = idx / 96, e = idx - k * 96;
    owT[idx] = ow[e * 192 + k];
  }
}

// ---------------------------------------------------------------------------
// K1: serpentine gather + LayerNorm over C=96.  out: xnT[c][b*8192 + l]
// ---------------------------------------------------------------------------
__global__ __launch_bounds__(256) void k1_serp_ln(const float* __restrict__ x,
    const float* __restrict__ gam, const float* __restrict__ bet,
    float* __restrict__ xnT) {
  const int b  = blockIdx.x >> 7;
  const int l0 = (blockIdx.x & 127) << 6;
  __shared__ float xs[96][65];
  __shared__ float mu[64], rs[64];
  const int tid = threadIdx.x;
  for (int idx = tid; idx < 96 * 64; idx += 256) {
    const int c = idx >> 6, l = idx & 63;
    const int lg = l0 + l;
    const int hh = (lg >> 5) & 31, w = lg & 31;
    const int lsrc = (hh & 1) ? (lg + 31 - 2 * w) : lg;
    xs[c][l] = x[(b * 96 + c) * LSEQ + lsrc];
  }
  __syncthreads();
  {
    const int l = tid >> 2, k = tid & 3;
    float s = 0.f, s2 = 0.f;
    for (int c = k; c < 96; c += 4) { const float v = xs[c][l]; s += v; s2 += v * v; }
    s  += __shfl_xor(s, 1);  s  += __shfl_xor(s, 2);
    s2 += __shfl_xor(s2, 1); s2 += __shfl_xor(s2, 2);
    if (k == 0) {
      const float m = s * (1.f / 96.f);
      const float var = s2 * (1.f / 96.f) - m * m;
      mu[l] = m; rs[l] = rsqrtf(var + 1e-5f);
    }
  }
  __syncthreads();
  for (int idx = tid; idx < 96 * 64; idx += 256) {
    const int c = idx >> 6, l = idx & 63;
    xnT[c * 16384 + (b << 13) + l0 + l] =
        (xs[c][l] - mu[l]) * rs[l] * gam[c] + bet[c];
  }
}

// ---------------------------------------------------------------------------
// K2: in_proj GEMM — LDS tiles padded to 68 (16B-aligned rows -> b128 reads).
// ---------------------------------------------------------------------------
__global__ __launch_bounds__(256) void k2_inproj(const float* __restrict__ xnT,
    const float* __restrict__ inwT, float* __restrict__ xz) {
  const int m0 = blockIdx.x << 6;
  const int e0 = blockIdx.y << 6;
  __shared__ float As[96][68];
  __shared__ float Ws[96][68];
  const int tid = threadIdx.x;
  for (int idx = tid; idx < 96 * 64; idx += 256) {
    const int k = idx >> 6, r = idx & 63;
    As[k][r] = xnT[(size_t)k * 16384 + m0 + r];
    Ws[k][r] = inwT[k * 384 + e0 + r];
  }
  __syncthreads();
  const int tx = tid & 15, ty = tid >> 4;
  const int la = tx << 2, ea = ty << 2;
  float acc[4][4] = {};
  for (int k = 0; k < 96; ++k) {
    const float4 av = *(const float4*)&As[k][la];
    const float4 bv = *(const float4*)&Ws[k][ea];
    acc[0][0] = fmaf(bv.x, av.x, acc[0][0]); acc[0][1] = fmaf(bv.x, av.y, acc[0][1]);
    acc[0][2] = fmaf(bv.x, av.z, acc[0][2]); acc[0][3] = fmaf(bv.x, av.w, acc[0][3]);
    acc[1][0] = fmaf(bv.y, av.x, acc[1][0]); acc[1][1] = fmaf(bv.y, av.y, acc[1][1]);
    acc[1][2] = fmaf(bv.y, av.z, acc[1][2]); acc[1][3] = fmaf(bv.y, av.w, acc[1][3]);
    acc[2][0] = fmaf(bv.z, av.x, acc[2][0]); acc[2][1] = fmaf(bv.z, av.y, acc[2][1]);
    acc[2][2] = fmaf(bv.z, av.z, acc[2][2]); acc[2][3] = fmaf(bv.z, av.w, acc[2][3]);
    acc[3][0] = fmaf(bv.w, av.x, acc[3][0]); acc[3][1] = fmaf(bv.w, av.y, acc[3][1]);
    acc[3][2] = fmaf(bv.w, av.z, acc[3][2]); acc[3][3] = fmaf(bv.w, av.w, acc[3][3]);
  }
  const int b = m0 >> 13, l0 = m0 & (LSEQ - 1);
  const bool dos = (e0 >= 192);
#pragma unroll
  for (int j = 0; j < 4; ++j) {
    const int e = e0 + ea + j;
    float4 v;
    v.x = acc[j][0]; v.y = acc[j][1]; v.z = acc[j][2]; v.w = acc[j][3];
    if (dos) {
      v.x = v.x / (1.f + __expf(-v.x)); v.y = v.y / (1.f + __expf(-v.y));
      v.z = v.z / (1.f + __expf(-v.z)); v.w = v.w / (1.f + __expf(-v.w));
    }
    *(float4*)(&xz[((size_t)b * 384 + e) * LSEQ + l0 + la]) = v;
  }
}

// ---------------------------------------------------------------------------
// K3a: depthwise conv + silu for BOTH directions (shared xz read).
// ---------------------------------------------------------------------------
__global__ __launch_bounds__(256) void k3a_conv(const float* __restrict__ xz,
    const float* __restrict__ cw_f, const float* __restrict__ cb_f,
    const float* __restrict__ cw_b, const float* __restrict__ cb_b,
    float* __restrict__ xc) {
  const int l = (blockIdx.x << 8) + threadIdx.x;
  const int d = blockIdx.y, b = blockIdx.z;
  const float* xin = xz + ((size_t)b * 384 + d) * LSEQ;
  float xv[7];
#pragma unroll
  for (int j = -3; j <= 3; ++j) {
    const int ls = l + j;
    xv[j + 3] = ((unsigned)ls < LSEQ) ? xin[ls] : 0.f;
  }
  float af = cb_f[d], ab = cb_b[d];
#pragma unroll
  for (int j = 0; j < 4; ++j) {
    af = fmaf(cw_f[d * 4 + j], xv[j], af);
    ab = fmaf(cw_b[d * 4 + j], xv[6 - j], ab);
  }
  xc[((size_t)(b)       * 192 + d) * LSEQ + l] = af / (1.f + __expf(-af));
  xc[((size_t)(2 + b)   * 192 + d) * LSEQ + l] = ab / (1.f + __expf(-ab));
}

// ---------------------------------------------------------------------------
// K3b1: x_proj GEMM — literal k2 template (R14 lesson: stop bespoke shapes).
// M = 4 dirb x 8192 l, N = 64 (40 useful), K = 192 in two 96-chunks.
// out: dbl[dirb][r<40][l]
// ---------------------------------------------------------------------------
__global__ __launch_bounds__(256) void k3b1_xproj(const float* __restrict__ xc,
    const float* __restrict__ xwT, float* __restrict__ dbl) {
  const int dirb = blockIdx.x >> 7, dir = dirb >> 1;
  const int l0 = (blockIdx.x & 127) << 6;
  __shared__ float As[96][68];
  __shared__ float Ws[96][68];
  const int tid = threadIdx.x;
  const float* pcBase = xc + (size_t)dirb * 192 * LSEQ + l0;
  const float* wt = xwT + dir * 192 * 64;
  const int tx = tid & 15, ty = tid >> 4;
  const int la = tx << 2, ea = ty << 2;
  float acc[4][4] = {};
  for (int kc = 0; kc < 192; kc += 96) {
    if (kc) __syncthreads();
    for (int idx = tid; idx < 96 * 64; idx += 256) {
      const int k = idx >> 6, r = idx & 63;
      As[k][r] = pcBase[(size_t)(kc + k) * LSEQ + r];
      Ws[k][r] = wt[(kc + k) * 64 + r];
    }
    __syncthreads();
    for (int k = 0; k < 96; ++k) {
      const float4 av = *(const float4*)&As[k][la];
      const float4 bv = *(const float4*)&Ws[k][ea];
      acc[0][0] = fmaf(bv.x, av.x, acc[0][0]); acc[0][1] = fmaf(bv.x, av.y, acc[0][1]);
      acc[0][2] = fmaf(bv.x, av.z, acc[0][2]); acc[0][3] = fmaf(bv.x, av.w, acc[0][3]);
      acc[1][0] = fmaf(bv.y, av.x, acc[1][0]); acc[1][1] = fmaf(bv.y, av.y, acc[1][1]);
      acc[1][2] = fmaf(bv.y, av.z, acc[1][2]); acc[1][3] = fmaf(bv.y, av.w, acc[1][3]);
      acc[2][0] = fmaf(bv.z, av.x, acc[2][0]); acc[2][1] = fmaf(bv.z, av.y, acc[2][1]);
      acc[2][2] = fmaf(bv.z, av.z, acc[2][2]); acc[2][3] = fmaf(bv.z, av.w, acc[2][3]);
      acc[3][0] = fmaf(bv.w, av.x, acc[3][0]); acc[3][1] = fmaf(bv.w, av.y, acc[3][1]);
      acc[3][2] = fmaf(bv.w, av.z, acc[3][2]); acc[3][3] = fmaf(bv.w, av.w, acc[3][3]);
    }
  }
#pragma unroll
  for (int j = 0; j < 4; ++j) {
    const int r = ea + j;
    if (r < 40) {
      float4 v;
      v.x = acc[j][0]; v.y = acc[j][1]; v.z = acc[j][2]; v.w = acc[j][3];
      *(float4*)(&dbl[((size_t)dirb * 40 + r) * LSEQ + l0 + la]) = v;
    }
  }
}

// ---------------------------------------------------------------------------
// K3b2: dt_proj + softplus + B/C extraction from dbl.  Memory-bound,
// small LDS (dtw only) -> high occupancy.  grid (128 l-chunks, 4 dirb).
// ---------------------------------------------------------------------------
__global__ __launch_bounds__(256) void k3b2_dtbc(const float* __restrict__ dbl,
    const float* __restrict__ dtw_f, const float* __restrict__ dtb_f,
    const float* __restrict__ dtw_b, const float* __restrict__ dtb_b,
    float* __restrict__ dt, float* __restrict__ Bo, float* __restrict__ Co) {
  __shared__ float dtwl[1152];
  const int dirb = blockIdx.y, dir = dirb >> 1;
  const int tid = threadIdx.x;
  const int lane = tid & 63, w = tid >> 6;
  const int l0 = blockIdx.x << 6;
  const float* dtwp = dir ? dtw_b : dtw_f;
  for (int idx = tid; idx < 1152; idx += 256) dtwl[idx] = dtwp[idx];
  const float* pd = dbl + (size_t)dirb * 40 * LSEQ + l0;
  // B/C extraction (no barrier needed yet; independent of dtwl)
  {
    const int lq = tid >> 2, g = tid & 3;
    float vB[4], vC[4];
#pragma unroll
    for (int i = 0; i < 4; ++i) {
      vB[i] = pd[(size_t)(6 + 4 * g + i) * LSEQ + lq];
      vC[i] = pd[(size_t)(22 + 4 * g + i) * LSEQ + lq];
    }
    const size_t off = ((size_t)dirb * LSEQ + l0 + lq) * 16 + 4 * g;
    *(float4*)&Bo[off] = make_float4(vB[0], vB[1], vB[2], vB[3]);
    *(float4*)&Co[off] = make_float4(vC[0], vC[1], vC[2], vC[3]);
  }
  const float v0 = pd[(size_t)0 * LSEQ + lane], v1 = pd[(size_t)1 * LSEQ + lane],
              v2 = pd[(size_t)2 * LSEQ + lane], v3 = pd[(size_t)3 * LSEQ + lane],
              v4 = pd[(size_t)4 * LSEQ + lane], v5 = pd[(size_t)5 * LSEQ + lane];
  __syncthreads();
  const float* db = dir ? dtb_b : dtb_f;
  float* pdt = dt + (size_t)dirb * 192 * LSEQ + l0 + lane;
#pragma unroll 4
  for (int i = 0; i < 48; ++i) {
    const int d = w * 48 + i;
    float s = db[d];
    s = fmaf(dtwl[d * 6 + 0], v0, s);
    s = fmaf(dtwl[d * 6 + 1], v1, s);
    s = fmaf(dtwl[d * 6 + 2], v2, s);
    s = fmaf(dtwl[d * 6 + 3], v3, s);
    s = fmaf(dtwl[d * 6 + 4], v4, s);
    s = fmaf(dtwl[d * 6 + 5], v5, s);
    pdt[(size_t)d * LSEQ] = (s > 20.f) ? s : __logf(1.f + __expf(s));
  }
}

// ---------------------------------------------------------------------------
// Scan pass A — 2 states per lane: 8 lanes per d, 32 d-rows per block.
// ---------------------------------------------------------------------------
template<int DIR>
__device__ __forceinline__ void scanA_body(
    float2 (*sdt)[32][34], float (*sb)[TS][16],
    const float* __restrict__ dtg, const float* __restrict__ xcg,
    const float* __restrict__ pB, const float* __restrict__ Al,
    float* __restrict__ Pb, float* __restrict__ Hb, int b, int c, int dg) {
  const int tid = threadIdx.x;
  const int dl = tid >> 3, n = tid & 7;
  const int dirb = DIR * 2 + b;
  const int d = (dg << 5) + dl;
  const float Adn1 = -__expf(Al[d * 16 + n]);
  const float Adn2 = -__expf(Al[d * 16 + n + 8]);
  const size_t rowbase = ((size_t)(dirb * 192) + (dg << 5)) * LSEQ;
  const float* dtp = dtg + rowbase;
  const float* xcp = xcg + rowbase;
  const int c0 = c << 8;
  const int sr0 = tid >> 4, spr = (tid & 15) * 2, sr1 = sr0 + 16;
  const int wt = tid >> 2, wf = (tid & 3) * 4;
  {
    const int tc = c0 + (DIR ? (NST - 1) : 0) * TS;
    const float2 a0 = *(const float2*)&dtp[(size_t)sr0 * LSEQ + tc + spr];
    const float2 x0 = *(const float2*)&xcp[(size_t)sr0 * LSEQ + tc + spr];
    const float2 a1 = *(const float2*)&dtp[(size_t)sr1 * LSEQ + tc + spr];
    const float2 x1 = *(const float2*)&xcp[(size_t)sr1 * LSEQ + tc + spr];
    float4 k0; k0.x = a0.x; k0.y = a0.x * x0.x; k0.z = a0.y; k0.w = a0.y * x0.y;
    float4 k1; k1.x = a1.x; k1.y = a1.x * x1.x; k1.z = a1.y; k1.w = a1.y * x1.y;
    *(float4*)&sdt[0][sr0][spr] = k0;
    *(float4*)&sdt[0][sr1][spr] = k1;
    if (tid < 128) {
      const float4 bv = *(const float4*)&pB[(size_t)(tc + wt) * 16 + wf];
      *(float4*)&sb[0][wt][wf] = bv;
    }
  }
  __syncthreads();
  float h1 = 0.f, h2 = 0.f, dts = 0.f;
  int buf = 0;
  for (int i = 0; i < NST; ++i) {
    const int s = DIR ? (NST - 1 - i) : i;
    float2 a0 = make_float2(0.f, 0.f), x0 = a0, a1 = a0, x1 = a0;
    float4 bv = make_float4(0.f, 0.f, 0.f, 0.f);
    if (i + 1 < NST) {
      const int tn = c0 + (DIR ? (s - 1) : (s + 1)) * TS;
      a0 = *(const float2*)&dtp[(size_t)sr0 * LSEQ + tn + spr];
      x0 = *(const float2*)&xcp[(size_t)sr0 * LSEQ + tn + spr];
      a1 = *(const float2*)&dtp[(size_t)sr1 * LSEQ + tn + spr];
      x1 = *(const float2*)&xcp[(size_t)sr1 * LSEQ + tn + spr];
      if (tid < 128) bv = *(const float4*)&pB[(size_t)(tn + wt) * 16 + wf];
    }
#pragma unroll
    for (int tt = 0; tt < TS; ++tt) {
      const int t = DIR ? (TS - 1 - tt) : tt;
      const float2 xv = sdt[buf][dl][t];
      const float B1 = sb[buf][t][n];
      const float B2 = sb[buf][t][n + 8];
      const float e1 = __expf(xv.x * Adn1);
      const float e2 = __expf(xv.x * Adn2);
      h1 = fmaf(e1, h1, xv.y * B1);
      h2 = fmaf(e2, h2, xv.y * B2);
      dts += xv.x;
    }
    if (i + 1 < NST) {
      float4 k0; k0.x = a0.x; k0.y = a0.x * x0.x; k0.z = a0.y; k0.w = a0.y * x0.y;
      float4 k1; k1.x = a1.x; k1.y = a1.x * x1.x; k1.z = a1.y; k1.w = a1.y * x1.y;
      *(float4*)&sdt[buf ^ 1][sr0][spr] = k0;
      *(float4*)&sdt[buf ^ 1][sr1][spr] = k1;
      if (tid < 128) *(float4*)&sb[buf ^ 1][wt][wf] = bv;
    }
    __syncthreads();
    buf ^= 1;
  }
  const int o = ((dirb * 32 + c) * 192 + d) * 16 + n;
  Pb[o]     = __expf(dts * Adn1);
  Pb[o + 8] = __expf(dts * Adn2);
  Hb[o]     = h1;
  Hb[o + 8] = h2;
}

__global__ __launch_bounds__(256) void k4_scanA(const float* __restrict__ dtg,
    const float* __restrict__ xcg, const float* __restrict__ Bo,
    const float* __restrict__ Al_f, const float* __restrict__ Al_b,
    float* __restrict__ Pb, float* __restrict__ Hb) {
  __shared__ float2 sdt[2][32][34];
  __shared__ float sb[2][TS][16];
  const int b = blockIdx.y, c = blockIdx.x & 31, dg = blockIdx.x >> 5;
  const float* pB0 = Bo + (size_t)(0 * 2 + b) * LSEQ * 16;
  const float* pB1 = Bo + (size_t)(1 * 2 + b) * LSEQ * 16;
  if (blockIdx.z == 0) scanA_body<0>(sdt, sb, dtg, xcg, pB0, Al_f, Pb, Hb, b, c, dg);
  else                 scanA_body<1>(sdt, sb, dtg, xcg, pB1, Al_b, Pb, Hb, b, c, dg);
}

// ---------------------------------------------------------------------------
// K5: chunk-level prefix over 32 chunks
// ---------------------------------------------------------------------------
__global__ __launch_bounds__(256) void k5_scanB(const float* __restrict__ Pb,
    const float* __restrict__ Hb, float* __restrict__ H0) {
  const int g = blockIdx.x * 256 + threadIdx.x;
  const int dirb = g / 3072, dn = g - dirb * 3072;
  const int dir = dirb >> 1;
  const int base = dirb * (32 * 3072) + dn;
  float h = 0.f;
  if (dir == 0) {
    for (int c = 0; c < 32; ++c) {
      const int o = base + c * 3072;
      H0[o] = h;
      h = fmaf(Pb[o], h, Hb[o]);
    }
  } else {
    for (int c = 31; c >= 0; --c) {
      const int o = base + c * 3072;
      H0[o] = h;
      h = fmaf(Pb[o], h, Hb[o]);
    }
  }
}

// ---------------------------------------------------------------------------
// Scan pass C — 2 states per lane: 8 lanes per d, red8, 32 d-rows per block.
// ---------------------------------------------------------------------------
template<int DIR>
__device__ __forceinline__ void scanC_body(
    float2 (*sdt)[32][34], float2 (*sbc)[TS][16],
    const float* __restrict__ dtg, const float* __restrict__ xcg,
    const float* __restrict__ pB, const float* __restrict__ pC,
    const float* __restrict__ xz,
    const float* __restrict__ Al, const float* __restrict__ Dv_,
    const float* __restrict__ H0, float* __restrict__ yout,
    int b, int c, int dg) {
  const int tid = threadIdx.x;
  const int dl = tid >> 3, n = tid & 7;
  const int dirb = DIR * 2 + b;
  const int d = (dg << 5) + dl;
  const float Adn1 = -__expf(Al[d * 16 + n]);
  const float Adn2 = -__expf(Al[d * 16 + n + 8]);
  const float Dv = Dv_[d];
  const size_t rowbase = ((size_t)(dirb * 192) + (dg << 5)) * LSEQ;
  const float* dtp = dtg + rowbase;
  const float* xcp = xcg + rowbase;
  const float* xcq = xcg + ((size_t)(dirb * 192) + d) * LSEQ;
  const float* psp = xz + ((size_t)(b * 384) + 192 + d) * LSEQ;
  float* py = yout + ((size_t)(b * 192) + d) * LSEQ;
  const int o = ((dirb * 32 + c) * 192 + d) * 16 + n;
  float h1 = H0[o], h2 = H0[o + 8];
  const int c0 = c << 8;
  const int sr0 = tid >> 4, spr = (tid & 15) * 2, sr1 = sr0 + 16;
  const int sbt = tid >> 3, sbp = (tid & 7) * 2;
  float cx0, cx1, cx2, cx3, sp0, sp1, sp2, sp3;
  {
    const int tc = c0 + (DIR ? (NST - 1) : 0) * TS;
    const float2 a0 = *(const float2*)&dtp[(size_t)sr0 * LSEQ + tc + spr];
    const float2 x0 = *(const float2*)&xcp[(size_t)sr0 * LSEQ + tc + spr];
    const float2 a1 = *(const float2*)&dtp[(size_t)sr1 * LSEQ + tc + spr];
    const float2 x1 = *(const float2*)&xcp[(size_t)sr1 * LSEQ + tc + spr];
    const float2 b2 = *(const float2*)&pB[(size_t)(tc + sbt) * 16 + sbp];
    const float2 c2 = *(const float2*)&pC[(size_t)(tc + sbt) * 16 + sbp];
    float4 k0; k0.x = a0.x; k0.y = a0.x * x0.x; k0.z = a0.y; k0.w = a0.y * x0.y;
    float4 k1; k1.x = a1.x; k1.y = a1.x * x1.x; k1.z = a1.y; k1.w = a1.y * x1.y;
    *(float4*)&sdt[0][sr0][spr] = k0;
    *(float4*)&sdt[0][sr1][spr] = k1;
    *(float4*)&sbc[0][sbt][sbp] = make_float4(b2.x, c2.x, b2.y, c2.y);
    cx0 = xcq[tc + n];      cx1 = xcq[tc + 8 + n];
    cx2 = xcq[tc + 16 + n]; cx3 = xcq[tc + 24 + n];
    sp0 = psp[tc + n];      sp1 = psp[tc + 8 + n];
    sp2 = psp[tc + 16 + n]; sp3 = psp[tc + 24 + n];
  }
  __syncthreads();
  int buf = 0;
  for (int i = 0; i < NST; ++i) {
    const int s = DIR ? (NST - 1 - i) : i;
    const int t0 = c0 + s * TS;
    float2 a0 = make_float2(0.f, 0.f), x0 = a0, a1 = a0, x1 = a0, b2 = a0, c2 = a0;
    float nx0 = 0.f, nx1 = 0.f, nx2 = 0.f, nx3 = 0.f;
    float ns0 = 0.f, ns1 = 0.f, ns2 = 0.f, ns3 = 0.f;
    if (i + 1 < NST) {
      const int tn = c0 + (DIR ? (s - 1) : (s + 1)) * TS;
      a0 = *(const float2*)&dtp[(size_t)sr0 * LSEQ + tn + spr];
      x0 = *(const float2*)&xcp[(size_t)sr0 * LSEQ + tn + spr];
      a1 = *(const float2*)&dtp[(size_t)sr1 * LSEQ + tn + spr];
      x1 = *(const float2*)&xcp[(size_t)sr1 * LSEQ + tn + spr];
      b2 = *(const float2*)&pB[(size_t)(tn + sbt) * 16 + sbp];
      c2 = *(const float2*)&pC[(size_t)(tn + sbt) * 16 + sbp];
      nx0 = xcq[tn + n];      nx1 = xcq[tn + 8 + n];
      nx2 = xcq[tn + 16 + n]; nx3 = xcq[tn + 24 + n];
      ns0 = psp[tn + n];      ns1 = psp[tn + 8 + n];
      ns2 = psp[tn + 16 + n]; ns3 = psp[tn + 24 + n];
    }
    float pq0 = 0.f, pq1 = 0.f, pq2 = 0.f, pq3 = 0.f;
#pragma unroll
    for (int tt = 0; tt < TS; ++tt) {
      const int t = DIR ? (TS - 1 - tt) : tt;
      const float2 xv = sdt[buf][dl][t];
      const float2 v1 = sbc[buf][t][n];
      const float2 v2 = sbc[buf][t][n + 8];
      const float e1 = __expf(xv.x * Adn1);
      const float e2 = __expf(xv.x * Adn2);
      h1 = fmaf(e1, h1, xv.y * v1.x);
      h2 = fmaf(e2, h2, xv.y * v2.x);
      float p = fmaf(h2, v2.y, h1 * v1.y);
      p = red8(p);
      const bool m = ((t & 7) == n);
      if ((t >> 3) == 0)      pq0 = m ? p : pq0;
      else if ((t >> 3) == 1) pq1 = m ? p : pq1;
      else if ((t >> 3) == 2) pq2 = m ? p : pq2;
      else                    pq3 = m ? p : pq3;
    }
    py[t0 + n]      = fmaf(Dv, cx0, pq0) * sp0;
    py[t0 + 8 + n]  = fmaf(Dv, cx1, pq1) * sp1;
    py[t0 + 16 + n] = fmaf(Dv, cx2, pq2) * sp2;
    py[t0 + 24 + n] = fmaf(Dv, cx3, pq3) * sp3;
    if (i + 1 < NST) {
      float4 k0; k0.x = a0.x; k0.y = a0.x * x0.x; k0.z = a0.y; k0.w = a0.y * x0.y;
      float4 k1; k1.x = a1.x; k1.y = a1.x * x1.x; k1.z = a1.y; k1.w = a1.y * x1.y;
      *(float4*)&sdt[buf ^ 1][sr0][spr] = k0;
      *(float4*)&sdt[buf ^ 1][sr1][spr] = k1;
      *(float4*)&sbc[buf ^ 1][sbt][sbp] = make_float4(b2.x, c2.x, b2.y, c2.y);
      cx0 = nx0; cx1 = nx1; cx2 = nx2; cx3 = nx3;
      sp0 = ns0; sp1 = ns1; sp2 = ns2; sp3 = ns3;
    }
    __syncthreads();
    buf ^= 1;
  }
}

__global__ __launch_bounds__(256) void k6_scanC(const float* __restrict__ dtg,
    const float* __restrict__ xcg, const float* __restrict__ Bo,
    const float* __restrict__ Co, const float* __restrict__ xz,
    const float* __restrict__ Al_f, const float* __restrict__ Al_b,
    const float* __restrict__ D_f, const float* __restrict__ D_b,
    const float* __restrict__ H0,
    float* __restrict__ yf, float* __restrict__ yb) {
  __shared__ float2 sdt[2][32][34];
  __shared__ float2 sbc[2][TS][16];
  const int b = blockIdx.y, c = blockIdx.x & 31, dg = blockIdx.x >> 5;
  const float* pB0 = Bo + (size_t)(0 * 2 + b) * LSEQ * 16;
  const float* pB1 = Bo + (size_t)(1 * 2 + b) * LSEQ * 16;
  const float* pC0 = Co + (size_t)(0 * 2 + b) * LSEQ * 16;
  const float* pC1 = Co + (size_t)(1 * 2 + b) * LSEQ * 16;
  if (blockIdx.z == 0)
    scanC_body<0>(sdt, sbc, dtg, xcg, pB0, pC0, xz, Al_f, D_f, H0, yf, b, c, dg);
  else
    scanC_body<1>(sdt, sbc, dtg, xcg, pB1, pC1, xz, Al_b, D_b, H0, yb, b, c, dg);
}

// ---------------------------------------------------------------------------
// K7: out_proj GEMM — LDS-tile structure, As padded to 68 (b128 reads).
// ---------------------------------------------------------------------------
__global__ __launch_bounds__(256) void k7_outproj(const float* __restrict__ yf,
    const float* __restrict__ yb, const float* __restrict__ owT,
    float* __restrict__ out) {
  const int m0 = blockIdx.x << 6;
  const int e0 = blockIdx.y * 48;
  const int b = m0 >> 13, l0 = m0 & (LSEQ - 1);
  __shared__ float As[48][68];
  __shared__ float Ws[48][49];
  const int tid = threadIdx.x;
  const int tx = tid & 15, ty = tid >> 4;
  const int la = tx << 2, ea = ty * 3;
  float acc[3][4] = {};
  for (int kc = 0; kc < 192; kc += 48) {
    for (int idx = tid; idx < 48 * 64; idx += 256) {
      const int k = idx >> 6, l = idx & 63;
      const size_t off = ((size_t)b * 192 + kc + k) * LSEQ + l0 + l;
      As[k][l] = yf[off] + yb[off];
    }
    for (int idx = tid; idx < 48 * 48; idx += 256) {
      const int k = idx / 48, e = idx - k * 48;
      Ws[k][e] = owT[(kc + k) * 96 + e0 + e];
    }
    __syncthreads();
#pragma unroll 4
    for (int k = 0; k < 48; ++k) {
      const float4 a4 = *(const float4*)&As[k][la];
      const float w0 = Ws[k][ea], w1 = Ws[k][ea + 1], w2 = Ws[k][ea + 2];
      acc[0][0] = fmaf(w0, a4.x, acc[0][0]); acc[0][1] = fmaf(w0, a4.y, acc[0][1]);
      acc[0][2] = fmaf(w0, a4.z, acc[0][2]); acc[0][3] = fmaf(w0, a4.w, acc[0][3]);
      acc[1][0] = fmaf(w1, a4.x, acc[1][0]); acc[1][1] = fmaf(w1, a4.y, acc[1][1]);
      acc[1][2] = fmaf(w1, a4.z, acc[1][2]); acc[1][3] = fmaf(w1, a4.w, acc[1][3]);
      acc[2][0] = fmaf(w2, a4.x, acc[2][0]); acc[2][1] = fmaf(w2, a4.y, acc[2][1]);
      acc[2][2] = fmaf(w2, a4.z, acc[2][2]); acc[2][3] = fmaf(w2, a4.w, acc[2][3]);
    }
    __syncthreads();
  }
#pragma unroll
  for (int j = 0; j < 3; ++j) {
    const int e = e0 + ea + j;
#pragma unroll
    for (int i = 0; i < 4; ++i) {
      const int l = l0 + la + i;
      const int hh = (l >> 5) & 31, ww = l & 31;
      const int lp = (hh & 1) ? (l + 31 - 2 * ww) : l;
      out[((size_t)b * 96 + e) * LSEQ + lp] = acc[j][i];
    }
  }
}

// ---------------------------------------------------------------------------
extern "C" void kernel_launch(void* const* d_in, const int* in_sizes, int n_in,
                              void* d_out, int out_size, void* d_ws, size_t ws_size,
                              hipStream_t stream) {
  const float* x     = (const float*)d_in[0];
  const float* ln_g  = (const float*)d_in[1];
  const float* ln_b  = (const float*)d_in[2];
  const float* in_w  = (const float*)d_in[3];
  const float* cw_f  = (const float*)d_in[4];
  const float* cb_f  = (const float*)d_in[5];
  const float* xw_f  = (const float*)d_in[6];
  const float* dtw_f = (const float*)d_in[7];
  const float* dtb_f = (const float*)d_in[8];
  const float* Al_f  = (const float*)d_in[9];
  const float* D_f   = (const float*)d_in[10];
  const float* cw_b  = (const float*)d_in[11];
  const float* cb_b  = (const float*)d_in[12];
  const float* xw_b  = (const float*)d_in[13];
  const float* dtw_b = (const float*)d_in[14];
  const float* dtb_b = (const float*)d_in[15];
  const float* Al_b  = (const float*)d_in[16];
  const float* D_b   = (const float*)d_in[17];
  const float* ow    = (const float*)d_in[18];
  float* out = (float*)d_out;

  float* ws = (float*)d_ws;
  float* xnT  = ws; ws += (size_t)16384 * 96;
  float* xz   = ws; ws += (size_t)2 * 384 * LSEQ;
  float* xc   = ws; ws += (size_t)4 * 192 * LSEQ;
  float* dt   = ws; ws += (size_t)4 * 192 * LSEQ;
  float* dbl  = ws; ws += (size_t)4 * 40 * LSEQ;
  float* Bo   = ws; ws += (size_t)4 * LSEQ * 16;
  float* Co   = ws; ws += (size_t)4 * LSEQ * 16;
  float* yf   = ws; ws += (size_t)2 * 192 * LSEQ;
  float* yb   = ws; ws += (size_t)2 * 192 * LSEQ;
  float* Pb   = ws; ws += (size_t)4 * 32 * 192 * 16;
  float* Hb   = ws; ws += (size_t)4 * 32 * 192 * 16;
  float* H0   = ws; ws += (size_t)4 * 32 * 192 * 16;
  float* xwT  = ws; ws += (size_t)2 * 192 * 64;
  float* inwT = ws; ws += (size_t)96 * 384;
  float* owT  = ws; ws += (size_t)192 * 96;

  k0_wt<<<dim3(64), dim3(256), 0, stream>>>(xw_f, xw_b, in_w, ow, xwT, inwT, owT);
  k1_serp_ln<<<dim3(256), dim3(256), 0, stream>>>(x, ln_g, ln_b, xnT);
  k2_inproj<<<dim3(256, 6), dim3(256), 0, stream>>>(xnT, inwT, xz);
  k3a_conv<<<dim3(32, 192, 2), dim3(256), 0, stream>>>(xz, cw_f, cb_f, cw_b, cb_b, xc);
  k3b1_xproj<<<dim3(512), dim3(256), 0, stream>>>(xc, xwT, dbl);
  k3b2_dtbc<<<dim3(128, 4), dim3(256), 0, stream>>>(dbl,
      dtw_f, dtb_f, dtw_b, dtb_b, dt, Bo, Co);
  k4_scanA<<<dim3(192, 2, 2), dim3(256), 0, stream>>>(dt, xc, Bo,
      Al_f, Al_b, Pb, Hb);
  k5_scanB<<<dim3(48), dim3(256), 0, stream>>>(Pb, Hb, H0);
  k6_scanC<<<dim3(192, 2, 2), dim3(256), 0, stream>>>(dt, xc, Bo, Co,
      xz, Al_f, Al_b, D_f, D_b, H0, yf, yb);
  k7_outproj<<<dim3(256, 2), dim3(256), 0, stream>>>(yf, yb, owT, out);
}

// Round 16
// 168.657 us; speedup vs baseline: 1.1261x; 1.0576x over previous
//
#include <hip/hip_runtime.h>
#include <math.h>

#define LSEQ 8192
#define TS   32
#define NST  4
#define NCH  64

// ---------------------------------------------------------------------------
// DPP adds + red8 (sum over 8 contiguous lanes).
// ---------------------------------------------------------------------------
template<int CTRL>
__device__ __forceinline__ float dpp_add(float x) {
  const int y = __builtin_amdgcn_update_dpp(0, __float_as_int(x), CTRL, 0xF, 0xF, true);
  return x + __int_as_float(y);
}
__device__ __forceinline__ float red8(float x) {
  x = dpp_add<0xB1>(x);
  x = dpp_add<0x4E>(x);
  x += __int_as_float(__builtin_amdgcn_ds_swizzle(__float_as_int(x), 0x101F));
  return x;
}

// ---------------------------------------------------------------------------
// K0: weight re-layouts.
// ---------------------------------------------------------------------------
__global__ __launch_bounds__(256) void k0_wt(const float* __restrict__ xw_f,
    const float* __restrict__ xw_b, const float* __restrict__ in_w,
    const float* __restrict__ ow, float* __restrict__ xwT,
    float* __restrict__ inwT, float* __restrict__ owT) {
  const int step = gridDim.x * 256;
  const int t0 = blockIdx.x * 256 + threadIdx.x;
  for (int idx = t0; idx < 2 * 192 * 64; idx += step) {
    const int dir = idx / (192 * 64), rem = idx - dir * 192 * 64;
    const int k = rem >> 6, r = rem & 63;
    const float* w = dir ? xw_b : xw_f;
    xwT[idx] = (r < 38) ? w[r * 192 + k] : 0.f;
  }
  for (int idx = t0; idx < 96 * 384; idx += step) {
    const int k = idx / 384, e = idx - k * 384;
    inwT[idx] = in_w[e * 96 + k];
  }
  for (int idx = t0; idx < 192 * 96; idx += step) {
    const int k = idx / 96, e = idx - k * 96;
    owT[idx] = ow[e * 192 + k];
  }
}

// ---------------------------------------------------------------------------
// K1: serpentine gather + LayerNorm over C=96.  out: xnT[c][b*8192 + l]
// ---------------------------------------------------------------------------
__global__ __launch_bounds__(256) void k1_serp_ln(const float* __restrict__ x,
    const float* __restrict__ gam, const float* __restrict__ bet,
    float* __restrict__ xnT) {
  const int b  = blockIdx.x >> 7;
  const int l0 = (blockIdx.x & 127) << 6;
  __shared__ float xs[96][65];
  __shared__ float mu[64], rs[64];
  const int tid = threadIdx.x;
  for (int idx = tid; idx < 96 * 64; idx += 256) {
    const int c = idx >> 6, l = idx & 63;
    const int lg = l0 + l;
    const int hh = (lg >> 5) & 31, w = lg & 31;
    const int lsrc = (hh & 1) ? (lg + 31 - 2 * w) : lg;
    xs[c][l] = x[(b * 96 + c) * LSEQ + lsrc];
  }
  __syncthreads();
  {
    const int l = tid >> 2, k = tid & 3;
    float s = 0.f, s2 = 0.f;
    for (int c = k; c < 96; c += 4) { const float v = xs[c][l]; s += v; s2 += v * v; }
    s  += __shfl_xor(s, 1);  s  += __shfl_xor(s, 2);
    s2 += __shfl_xor(s2, 1); s2 += __shfl_xor(s2, 2);
    if (k == 0) {
      const float m = s * (1.f / 96.f);
      const float var = s2 * (1.f / 96.f) - m * m;
      mu[l] = m; rs[l] = rsqrtf(var + 1e-5f);
    }
  }
  __syncthreads();
  for (int idx = tid; idx < 96 * 64; idx += 256) {
    const int c = idx >> 6, l = idx & 63;
    xnT[c * 16384 + (b << 13) + l0 + l] =
        (xs[c][l] - mu[l]) * rs[l] * gam[c] + bet[c];
  }
}

// ---------------------------------------------------------------------------
// K2: in_proj GEMM — LDS tiles padded to 68 (16B-aligned rows -> b128 reads).
// ---------------------------------------------------------------------------
__global__ __launch_bounds__(256) void k2_inproj(const float* __restrict__ xnT,
    const float* __restrict__ inwT, float* __restrict__ xz) {
  const int m0 = blockIdx.x << 6;
  const int e0 = blockIdx.y << 6;
  __shared__ float As[96][68];
  __shared__ float Ws[96][68];
  const int tid = threadIdx.x;
  for (int idx = tid; idx < 96 * 64; idx += 256) {
    const int k = idx >> 6, r = idx & 63;
    As[k][r] = xnT[(size_t)k * 16384 + m0 + r];
    Ws[k][r] = inwT[k * 384 + e0 + r];
  }
  __syncthreads();
  const int tx = tid & 15, ty = tid >> 4;
  const int la = tx << 2, ea = ty << 2;
  float acc[4][4] = {};
  for (int k = 0; k < 96; ++k) {
    const float4 av = *(const float4*)&As[k][la];
    const float4 bv = *(const float4*)&Ws[k][ea];
    acc[0][0] = fmaf(bv.x, av.x, acc[0][0]); acc[0][1] = fmaf(bv.x, av.y, acc[0][1]);
    acc[0][2] = fmaf(bv.x, av.z, acc[0][2]); acc[0][3] = fmaf(bv.x, av.w, acc[0][3]);
    acc[1][0] = fmaf(bv.y, av.x, acc[1][0]); acc[1][1] = fmaf(bv.y, av.y, acc[1][1]);
    acc[1][2] = fmaf(bv.y, av.z, acc[1][2]); acc[1][3] = fmaf(bv.y, av.w, acc[1][3]);
    acc[2][0] = fmaf(bv.z, av.x, acc[2][0]); acc[2][1] = fmaf(bv.z, av.y, acc[2][1]);
    acc[2][2] = fmaf(bv.z, av.z, acc[2][2]); acc[2][3] = fmaf(bv.z, av.w, acc[2][3]);
    acc[3][0] = fmaf(bv.w, av.x, acc[3][0]); acc[3][1] = fmaf(bv.w, av.y, acc[3][1]);
    acc[3][2] = fmaf(bv.w, av.z, acc[3][2]); acc[3][3] = fmaf(bv.w, av.w, acc[3][3]);
  }
  const int b = m0 >> 13, l0 = m0 & (LSEQ - 1);
  const bool dos = (e0 >= 192);
#pragma unroll
  for (int j = 0; j < 4; ++j) {
    const int e = e0 + ea + j;
    float4 v;
    v.x = acc[j][0]; v.y = acc[j][1]; v.z = acc[j][2]; v.w = acc[j][3];
    if (dos) {
      v.x = v.x / (1.f + __expf(-v.x)); v.y = v.y / (1.f + __expf(-v.y));
      v.z = v.z / (1.f + __expf(-v.z)); v.w = v.w / (1.f + __expf(-v.w));
    }
    *(float4*)(&xz[((size_t)b * 384 + e) * LSEQ + l0 + la]) = v;
  }
}

// ---------------------------------------------------------------------------
// K3a: depthwise conv + silu for BOTH directions (shared xz read).
// ---------------------------------------------------------------------------
__global__ __launch_bounds__(256) void k3a_conv(const float* __restrict__ xz,
    const float* __restrict__ cw_f, const float* __restrict__ cb_f,
    const float* __restrict__ cw_b, const float* __restrict__ cb_b,
    float* __restrict__ xc) {
  const int l = (blockIdx.x << 8) + threadIdx.x;
  const int d = blockIdx.y, b = blockIdx.z;
  const float* xin = xz + ((size_t)b * 384 + d) * LSEQ;
  float xv[7];
#pragma unroll
  for (int j = -3; j <= 3; ++j) {
    const int ls = l + j;
    xv[j + 3] = ((unsigned)ls < LSEQ) ? xin[ls] : 0.f;
  }
  float af = cb_f[d], ab = cb_b[d];
#pragma unroll
  for (int j = 0; j < 4; ++j) {
    af = fmaf(cw_f[d * 4 + j], xv[j], af);
    ab = fmaf(cw_b[d * 4 + j], xv[6 - j], ab);
  }
  xc[((size_t)(b)       * 192 + d) * LSEQ + l] = af / (1.f + __expf(-af));
  xc[((size_t)(2 + b)   * 192 + d) * LSEQ + l] = ab / (1.f + __expf(-ab));
}

// ---------------------------------------------------------------------------
// K3b1: x_proj GEMM — k2 template.  out: dbl[dirb][r<40][l]
// ---------------------------------------------------------------------------
__global__ __launch_bounds__(256) void k3b1_xproj(const float* __restrict__ xc,
    const float* __restrict__ xwT, float* __restrict__ dbl) {
  const int dirb = blockIdx.x >> 7, dir = dirb >> 1;
  const int l0 = (blockIdx.x & 127) << 6;
  __shared__ float As[96][68];
  __shared__ float Ws[96][68];
  const int tid = threadIdx.x;
  const float* pcBase = xc + (size_t)dirb * 192 * LSEQ + l0;
  const float* wt = xwT + dir * 192 * 64;
  const int tx = tid & 15, ty = tid >> 4;
  const int la = tx << 2, ea = ty << 2;
  float acc[4][4] = {};
  for (int kc = 0; kc < 192; kc += 96) {
    if (kc) __syncthreads();
    for (int idx = tid; idx < 96 * 64; idx += 256) {
      const int k = idx >> 6, r = idx & 63;
      As[k][r] = pcBase[(size_t)(kc + k) * LSEQ + r];
      Ws[k][r] = wt[(kc + k) * 64 + r];
    }
    __syncthreads();
    for (int k = 0; k < 96; ++k) {
      const float4 av = *(const float4*)&As[k][la];
      const float4 bv = *(const float4*)&Ws[k][ea];
      acc[0][0] = fmaf(bv.x, av.x, acc[0][0]); acc[0][1] = fmaf(bv.x, av.y, acc[0][1]);
      acc[0][2] = fmaf(bv.x, av.z, acc[0][2]); acc[0][3] = fmaf(bv.x, av.w, acc[0][3]);
      acc[1][0] = fmaf(bv.y, av.x, acc[1][0]); acc[1][1] = fmaf(bv.y, av.y, acc[1][1]);
      acc[1][2] = fmaf(bv.y, av.z, acc[1][2]); acc[1][3] = fmaf(bv.y, av.w, acc[1][3]);
      acc[2][0] = fmaf(bv.z, av.x, acc[2][0]); acc[2][1] = fmaf(bv.z, av.y, acc[2][1]);
      acc[2][2] = fmaf(bv.z, av.z, acc[2][2]); acc[2][3] = fmaf(bv.z, av.w, acc[2][3]);
      acc[3][0] = fmaf(bv.w, av.x, acc[3][0]); acc[3][1] = fmaf(bv.w, av.y, acc[3][1]);
      acc[3][2] = fmaf(bv.w, av.z, acc[3][2]); acc[3][3] = fmaf(bv.w, av.w, acc[3][3]);
    }
  }
#pragma unroll
  for (int j = 0; j < 4; ++j) {
    const int r = ea + j;
    if (r < 40) {
      float4 v;
      v.x = acc[j][0]; v.y = acc[j][1]; v.z = acc[j][2]; v.w = acc[j][3];
      *(float4*)(&dbl[((size_t)dirb * 40 + r) * LSEQ + l0 + la]) = v;
    }
  }
}

// ---------------------------------------------------------------------------
// K3b2: dt_proj + softplus + B/C extraction from dbl.
// ---------------------------------------------------------------------------
__global__ __launch_bounds__(256) void k3b2_dtbc(const float* __restrict__ dbl,
    const float* __restrict__ dtw_f, const float* __restrict__ dtb_f,
    const float* __restrict__ dtw_b, const float* __restrict__ dtb_b,
    float* __restrict__ dt, float* __restrict__ Bo, float* __restrict__ Co) {
  __shared__ float dtwl[1152];
  const int dirb = blockIdx.y, dir = dirb >> 1;
  const int tid = threadIdx.x;
  const int lane = tid & 63, w = tid >> 6;
  const int l0 = blockIdx.x << 6;
  const float* dtwp = dir ? dtw_b : dtw_f;
  for (int idx = tid; idx < 1152; idx += 256) dtwl[idx] = dtwp[idx];
  const float* pd = dbl + (size_t)dirb * 40 * LSEQ + l0;
  {
    const int lq = tid >> 2, g = tid & 3;
    float vB[4], vC[4];
#pragma unroll
    for (int i = 0; i < 4; ++i) {
      vB[i] = pd[(size_t)(6 + 4 * g + i) * LSEQ + lq];
      vC[i] = pd[(size_t)(22 + 4 * g + i) * LSEQ + lq];
    }
    const size_t off = ((size_t)dirb * LSEQ + l0 + lq) * 16 + 4 * g;
    *(float4*)&Bo[off] = make_float4(vB[0], vB[1], vB[2], vB[3]);
    *(float4*)&Co[off] = make_float4(vC[0], vC[1], vC[2], vC[3]);
  }
  const float v0 = pd[(size_t)0 * LSEQ + lane], v1 = pd[(size_t)1 * LSEQ + lane],
              v2 = pd[(size_t)2 * LSEQ + lane], v3 = pd[(size_t)3 * LSEQ + lane],
              v4 = pd[(size_t)4 * LSEQ + lane], v5 = pd[(size_t)5 * LSEQ + lane];
  __syncthreads();
  const float* db = dir ? dtb_b : dtb_f;
  float* pdt = dt + (size_t)dirb * 192 * LSEQ + l0 + lane;
#pragma unroll 4
  for (int i = 0; i < 48; ++i) {
    const int d = w * 48 + i;
    float s = db[d];
    s = fmaf(dtwl[d * 6 + 0], v0, s);
    s = fmaf(dtwl[d * 6 + 1], v1, s);
    s = fmaf(dtwl[d * 6 + 2], v2, s);
    s = fmaf(dtwl[d * 6 + 3], v3, s);
    s = fmaf(dtwl[d * 6 + 4], v4, s);
    s = fmaf(dtwl[d * 6 + 5], v5, s);
    pdt[(size_t)d * LSEQ] = (s > 20.f) ? s : __logf(1.f + __expf(s));
  }
}

// ---------------------------------------------------------------------------
// Scan pass A — 2 states per lane; NCH=64 chunks of 128 t (R15: 32 chunks
// gave only 3 blocks/CU -> 23% occupancy; 64 chunks -> 6 blocks/CU).
// ---------------------------------------------------------------------------
template<int DIR>
__device__ __forceinline__ void scanA_body(
    float2 (*sdt)[32][34], float (*sb)[TS][16],
    const float* __restrict__ dtg, const float* __restrict__ xcg,
    const float* __restrict__ pB, const float* __restrict__ Al,
    float* __restrict__ Pb, float* __restrict__ Hb, int b, int c, int dg) {
  const int tid = threadIdx.x;
  const int dl = tid >> 3, n = tid & 7;
  const int dirb = DIR * 2 + b;
  const int d = (dg << 5) + dl;
  const float Adn1 = -__expf(Al[d * 16 + n]);
  const float Adn2 = -__expf(Al[d * 16 + n + 8]);
  const size_t rowbase = ((size_t)(dirb * 192) + (dg << 5)) * LSEQ;
  const float* dtp = dtg + rowbase;
  const float* xcp = xcg + rowbase;
  const int c0 = c << 7;
  const int sr0 = tid >> 4, spr = (tid & 15) * 2, sr1 = sr0 + 16;
  const int wt = tid >> 2, wf = (tid & 3) * 4;
  {
    const int tc = c0 + (DIR ? (NST - 1) : 0) * TS;
    const float2 a0 = *(const float2*)&dtp[(size_t)sr0 * LSEQ + tc + spr];
    const float2 x0 = *(const float2*)&xcp[(size_t)sr0 * LSEQ + tc + spr];
    const float2 a1 = *(const float2*)&dtp[(size_t)sr1 * LSEQ + tc + spr];
    const float2 x1 = *(const float2*)&xcp[(size_t)sr1 * LSEQ + tc + spr];
    float4 k0; k0.x = a0.x; k0.y = a0.x * x0.x; k0.z = a0.y; k0.w = a0.y * x0.y;
    float4 k1; k1.x = a1.x; k1.y = a1.x * x1.x; k1.z = a1.y; k1.w = a1.y * x1.y;
    *(float4*)&sdt[0][sr0][spr] = k0;
    *(float4*)&sdt[0][sr1][spr] = k1;
    if (tid < 128) {
      const float4 bv = *(const float4*)&pB[(size_t)(tc + wt) * 16 + wf];
      *(float4*)&sb[0][wt][wf] = bv;
    }
  }
  __syncthreads();
  float h1 = 0.f, h2 = 0.f, dts = 0.f;
  int buf = 0;
  for (int i = 0; i < NST; ++i) {
    const int s = DIR ? (NST - 1 - i) : i;
    float2 a0 = make_float2(0.f, 0.f), x0 = a0, a1 = a0, x1 = a0;
    float4 bv = make_float4(0.f, 0.f, 0.f, 0.f);
    if (i + 1 < NST) {
      const int tn = c0 + (DIR ? (s - 1) : (s + 1)) * TS;
      a0 = *(const float2*)&dtp[(size_t)sr0 * LSEQ + tn + spr];
      x0 = *(const float2*)&xcp[(size_t)sr0 * LSEQ + tn + spr];
      a1 = *(const float2*)&dtp[(size_t)sr1 * LSEQ + tn + spr];
      x1 = *(const float2*)&xcp[(size_t)sr1 * LSEQ + tn + spr];
      if (tid < 128) bv = *(const float4*)&pB[(size_t)(tn + wt) * 16 + wf];
    }
#pragma unroll
    for (int tt = 0; tt < TS; ++tt) {
      const int t = DIR ? (TS - 1 - tt) : tt;
      const float2 xv = sdt[buf][dl][t];
      const float B1 = sb[buf][t][n];
      const float B2 = sb[buf][t][n + 8];
      const float e1 = __expf(xv.x * Adn1);
      const float e2 = __expf(xv.x * Adn2);
      h1 = fmaf(e1, h1, xv.y * B1);
      h2 = fmaf(e2, h2, xv.y * B2);
      dts += xv.x;
    }
    if (i + 1 < NST) {
      float4 k0; k0.x = a0.x; k0.y = a0.x * x0.x; k0.z = a0.y; k0.w = a0.y * x0.y;
      float4 k1; k1.x = a1.x; k1.y = a1.x * x1.x; k1.z = a1.y; k1.w = a1.y * x1.y;
      *(float4*)&sdt[buf ^ 1][sr0][spr] = k0;
      *(float4*)&sdt[buf ^ 1][sr1][spr] = k1;
      if (tid < 128) *(float4*)&sb[buf ^ 1][wt][wf] = bv;
    }
    __syncthreads();
    buf ^= 1;
  }
  const int o = ((dirb * NCH + c) * 192 + d) * 16 + n;
  Pb[o]     = __expf(dts * Adn1);
  Pb[o + 8] = __expf(dts * Adn2);
  Hb[o]     = h1;
  Hb[o + 8] = h2;
}

__global__ __launch_bounds__(256) void k4_scanA(const float* __restrict__ dtg,
    const float* __restrict__ xcg, const float* __restrict__ Bo,
    const float* __restrict__ Al_f, const float* __restrict__ Al_b,
    float* __restrict__ Pb, float* __restrict__ Hb) {
  __shared__ float2 sdt[2][32][34];
  __shared__ float sb[2][TS][16];
  const int b = blockIdx.y, c = blockIdx.x & 63, dg = blockIdx.x >> 6;
  const float* pB0 = Bo + (size_t)(0 * 2 + b) * LSEQ * 16;
  const float* pB1 = Bo + (size_t)(1 * 2 + b) * LSEQ * 16;
  if (blockIdx.z == 0) scanA_body<0>(sdt, sb, dtg, xcg, pB0, Al_f, Pb, Hb, b, c, dg);
  else                 scanA_body<1>(sdt, sb, dtg, xcg, pB1, Al_b, Pb, Hb, b, c, dg);
}

// ---------------------------------------------------------------------------
// K5: chunk-level prefix over NCH=64 chunks
// ---------------------------------------------------------------------------
__global__ __launch_bounds__(256) void k5_scanB(const float* __restrict__ Pb,
    const float* __restrict__ Hb, float* __restrict__ H0) {
  const int g = blockIdx.x * 256 + threadIdx.x;
  const int dirb = g / 3072, dn = g - dirb * 3072;
  const int dir = dirb >> 1;
  const int base = dirb * (NCH * 3072) + dn;
  float h = 0.f;
  if (dir == 0) {
    for (int c = 0; c < NCH; ++c) {
      const int o = base + c * 3072;
      H0[o] = h;
      h = fmaf(Pb[o], h, Hb[o]);
    }
  } else {
    for (int c = NCH - 1; c >= 0; --c) {
      const int o = base + c * 3072;
      H0[o] = h;
      h = fmaf(Pb[o], h, Hb[o]);
    }
  }
}

// ---------------------------------------------------------------------------
// Scan pass C — 2 states per lane, NCH=64 chunks of 128 t.
// ---------------------------------------------------------------------------
template<int DIR>
__device__ __forceinline__ void scanC_body(
    float2 (*sdt)[32][34], float2 (*sbc)[TS][16],
    const float* __restrict__ dtg, const float* __restrict__ xcg,
    const float* __restrict__ pB, const float* __restrict__ pC,
    const float* __restrict__ xz,
    const float* __restrict__ Al, const float* __restrict__ Dv_,
    const float* __restrict__ H0, float* __restrict__ yout,
    int b, int c, int dg) {
  const int tid = threadIdx.x;
  const int dl = tid >> 3, n = tid & 7;
  const int dirb = DIR * 2 + b;
  const int d = (dg << 5) + dl;
  const float Adn1 = -__expf(Al[d * 16 + n]);
  const float Adn2 = -__expf(Al[d * 16 + n + 8]);
  const float Dv = Dv_[d];
  const size_t rowbase = ((size_t)(dirb * 192) + (dg << 5)) * LSEQ;
  const float* dtp = dtg + rowbase;
  const float* xcp = xcg + rowbase;
  const float* xcq = xcg + ((size_t)(dirb * 192) + d) * LSEQ;
  const float* psp = xz + ((size_t)(b * 384) + 192 + d) * LSEQ;
  float* py = yout + ((size_t)(b * 192) + d) * LSEQ;
  const int o = ((dirb * NCH + c) * 192 + d) * 16 + n;
  float h1 = H0[o], h2 = H0[o + 8];
  const int c0 = c << 7;
  const int sr0 = tid >> 4, spr = (tid & 15) * 2, sr1 = sr0 + 16;
  const int sbt = tid >> 3, sbp = (tid & 7) * 2;
  float cx0, cx1, cx2, cx3, sp0, sp1, sp2, sp3;
  {
    const int tc = c0 + (DIR ? (NST - 1) : 0) * TS;
    const float2 a0 = *(const float2*)&dtp[(size_t)sr0 * LSEQ + tc + spr];
    const float2 x0 = *(const float2*)&xcp[(size_t)sr0 * LSEQ + tc + spr];
    const float2 a1 = *(const float2*)&dtp[(size_t)sr1 * LSEQ + tc + spr];
    const float2 x1 = *(const float2*)&xcp[(size_t)sr1 * LSEQ + tc + spr];
    const float2 b2 = *(const float2*)&pB[(size_t)(tc + sbt) * 16 + sbp];
    const float2 c2 = *(const float2*)&pC[(size_t)(tc + sbt) * 16 + sbp];
    float4 k0; k0.x = a0.x; k0.y = a0.x * x0.x; k0.z = a0.y; k0.w = a0.y * x0.y;
    float4 k1; k1.x = a1.x; k1.y = a1.x * x1.x; k1.z = a1.y; k1.w = a1.y * x1.y;
    *(float4*)&sdt[0][sr0][spr] = k0;
    *(float4*)&sdt[0][sr1][spr] = k1;
    *(float4*)&sbc[0][sbt][sbp] = make_float4(b2.x, c2.x, b2.y, c2.y);
    cx0 = xcq[tc + n];      cx1 = xcq[tc + 8 + n];
    cx2 = xcq[tc + 16 + n]; cx3 = xcq[tc + 24 + n];
    sp0 = psp[tc + n];      sp1 = psp[tc + 8 + n];
    sp2 = psp[tc + 16 + n]; sp3 = psp[tc + 24 + n];
  }
  __syncthreads();
  int buf = 0;
  for (int i = 0; i < NST; ++i) {
    const int s = DIR ? (NST - 1 - i) : i;
    const int t0 = c0 + s * TS;
    float2 a0 = make_float2(0.f, 0.f), x0 = a0, a1 = a0, x1 = a0, b2 = a0, c2 = a0;
    float nx0 = 0.f, nx1 = 0.f, nx2 = 0.f, nx3 = 0.f;
    float ns0 = 0.f, ns1 = 0.f, ns2 = 0.f, ns3 = 0.f;
    if (i + 1 < NST) {
      const int tn = c0 + (DIR ? (s - 1) : (s + 1)) * TS;
      a0 = *(const float2*)&dtp[(size_t)sr0 * LSEQ + tn + spr];
      x0 = *(const float2*)&xcp[(size_t)sr0 * LSEQ + tn + spr];
      a1 = *(const float2*)&dtp[(size_t)sr1 * LSEQ + tn + spr];
      x1 = *(const float2*)&xcp[(size_t)sr1 * LSEQ + tn + spr];
      b2 = *(const float2*)&pB[(size_t)(tn + sbt) * 16 + sbp];
      c2 = *(const float2*)&pC[(size_t)(tn + sbt) * 16 + sbp];
      nx0 = xcq[tn + n];      nx1 = xcq[tn + 8 + n];
      nx2 = xcq[tn + 16 + n]; nx3 = xcq[tn + 24 + n];
      ns0 = psp[tn + n];      ns1 = psp[tn + 8 + n];
      ns2 = psp[tn + 16 + n]; ns3 = psp[tn + 24 + n];
    }
    float pq0 = 0.f, pq1 = 0.f, pq2 = 0.f, pq3 = 0.f;
#pragma unroll
    for (int tt = 0; tt < TS; ++tt) {
      const int t = DIR ? (TS - 1 - tt) : tt;
      const float2 xv = sdt[buf][dl][t];
      const float2 v1 = sbc[buf][t][n];
      const float2 v2 = sbc[buf][t][n + 8];
      const float e1 = __expf(xv.x * Adn1);
      const float e2 = __expf(xv.x * Adn2);
      h1 = fmaf(e1, h1, xv.y * v1.x);
      h2 = fmaf(e2, h2, xv.y * v2.x);
      float p = fmaf(h2, v2.y, h1 * v1.y);
      p = red8(p);
      const bool m = ((t & 7) == n);
      if ((t >> 3) == 0)      pq0 = m ? p : pq0;
      else if ((t >> 3) == 1) pq1 = m ? p : pq1;
      else if ((t >> 3) == 2) pq2 = m ? p : pq2;
      else                    pq3 = m ? p : pq3;
    }
    py[t0 + n]      = fmaf(Dv, cx0, pq0) * sp0;
    py[t0 + 8 + n]  = fmaf(Dv, cx1, pq1) * sp1;
    py[t0 + 16 + n] = fmaf(Dv, cx2, pq2) * sp2;
    py[t0 + 24 + n] = fmaf(Dv, cx3, pq3) * sp3;
    if (i + 1 < NST) {
      float4 k0; k0.x = a0.x; k0.y = a0.x * x0.x; k0.z = a0.y; k0.w = a0.y * x0.y;
      float4 k1; k1.x = a1.x; k1.y = a1.x * x1.x; k1.z = a1.y; k1.w = a1.y * x1.y;
      *(float4*)&sdt[buf ^ 1][sr0][spr] = k0;
      *(float4*)&sdt[buf ^ 1][sr1][spr] = k1;
      *(float4*)&sbc[buf ^ 1][sbt][sbp] = make_float4(b2.x, c2.x, b2.y, c2.y);
      cx0 = nx0; cx1 = nx1; cx2 = nx2; cx3 = nx3;
      sp0 = ns0; sp1 = ns1; sp2 = ns2; sp3 = ns3;
    }
    __syncthreads();
    buf ^= 1;
  }
}

__global__ __launch_bounds__(256) void k6_scanC(const float* __restrict__ dtg,
    const float* __restrict__ xcg, const float* __restrict__ Bo,
    const float* __restrict__ Co, const float* __restrict__ xz,
    const float* __restrict__ Al_f, const float* __restrict__ Al_b,
    const float* __restrict__ D_f, const float* __restrict__ D_b,
    const float* __restrict__ H0,
    float* __restrict__ yf, float* __restrict__ yb) {
  __shared__ float2 sdt[2][32][34];
  __shared__ float2 sbc[2][TS][16];
  const int b = blockIdx.y, c = blockIdx.x & 63, dg = blockIdx.x >> 6;
  const float* pB0 = Bo + (size_t)(0 * 2 + b) * LSEQ * 16;
  const float* pB1 = Bo + (size_t)(1 * 2 + b) * LSEQ * 16;
  const float* pC0 = Co + (size_t)(0 * 2 + b) * LSEQ * 16;
  const float* pC1 = Co + (size_t)(1 * 2 + b) * LSEQ * 16;
  if (blockIdx.z == 0)
    scanC_body<0>(sdt, sbc, dtg, xcg, pB0, pC0, xz, Al_f, D_f, H0, yf, b, c, dg);
  else
    scanC_body<1>(sdt, sbc, dtg, xcg, pB1, pC1, xz, Al_b, D_b, H0, yb, b, c, dg);
}

// ---------------------------------------------------------------------------
// K7: out_proj GEMM — LDS-tile structure, As padded to 68 (b128 reads).
// ---------------------------------------------------------------------------
__global__ __launch_bounds__(256) void k7_outproj(const float* __restrict__ yf,
    const float* __restrict__ yb, const float* __restrict__ owT,
    float* __restrict__ out) {
  const int m0 = blockIdx.x << 6;
  const int e0 = blockIdx.y * 48;
  const int b = m0 >> 13, l0 = m0 & (LSEQ - 1);
  __shared__ float As[48][68];
  __shared__ float Ws[48][49];
  const int tid = threadIdx.x;
  const int tx = tid & 15, ty = tid >> 4;
  const int la = tx << 2, ea = ty * 3;
  float acc[3][4] = {};
  for (int kc = 0; kc < 192; kc += 48) {
    for (int idx = tid; idx < 48 * 64; idx += 256) {
      const int k = idx >> 6, l = idx & 63;
      const size_t off = ((size_t)b * 192 + kc + k) * LSEQ + l0 + l;
      As[k][l] = yf[off] + yb[off];
    }
    for (int idx = tid; idx < 48 * 48; idx += 256) {
      const int k = idx / 48, e = idx - k * 48;
      Ws[k][e] = owT[(kc + k) * 96 + e0 + e];
    }
    __syncthreads();
#pragma unroll 4
    for (int k = 0; k < 48; ++k) {
      const float4 a4 = *(const float4*)&As[k][la];
      const float w0 = Ws[k][ea], w1 = Ws[k][ea + 1], w2 = Ws[k][ea + 2];
      acc[0][0] = fmaf(w0, a4.x, acc[0][0]); acc[0][1] = fmaf(w0, a4.y, acc[0][1]);
      acc[0][2] = fmaf(w0, a4.z, acc[0][2]); acc[0][3] = fmaf(w0, a4.w, acc[0][3]);
      acc[1][0] = fmaf(w1, a4.x, acc[1][0]); acc[1][1] = fmaf(w1, a4.y, acc[1][1]);
      acc[1][2] = fmaf(w1, a4.z, acc[1][2]); acc[1][3] = fmaf(w1, a4.w, acc[1][3]);
      acc[2][0] = fmaf(w2, a4.x, acc[2][0]); acc[2][1] = fmaf(w2, a4.y, acc[2][1]);
      acc[2][2] = fmaf(w2, a4.z, acc[2][2]); acc[2][3] = fmaf(w2, a4.w, acc[2][3]);
    }
    __syncthreads();
  }
#pragma unroll
  for (int j = 0; j < 3; ++j) {
    const int e = e0 + ea + j;
#pragma unroll
    for (int i = 0; i < 4; ++i) {
      const int l = l0 + la + i;
      const int hh = (l >> 5) & 31, ww = l & 31;
      const int lp = (hh & 1) ? (l + 31 - 2 * ww) : l;
      out[((size_t)b * 96 + e) * LSEQ + lp] = acc[j][i];
    }
  }
}

// ---------------------------------------------------------------------------
extern "C" void kernel_launch(void* const* d_in, const int* in_sizes, int n_in,
                              void* d_out, int out_size, void* d_ws, size_t ws_size,
                              hipStream_t stream) {
  const float* x     = (const float*)d_in[0];
  const float* ln_g  = (const float*)d_in[1];
  const float* ln_b  = (const float*)d_in[2];
  const float* in_w  = (const float*)d_in[3];
  const float* cw_f  = (const float*)d_in[4];
  const float* cb_f  = (const float*)d_in[5];
  const float* xw_f  = (const float*)d_in[6];
  const float* dtw_f = (const float*)d_in[7];
  const float* dtb_f = (const float*)d_in[8];
  const float* Al_f  = (const float*)d_in[9];
  const float* D_f   = (const float*)d_in[10];
  const float* cw_b  = (const float*)d_in[11];
  const float* cb_b  = (const float*)d_in[12];
  const float* xw_b  = (const float*)d_in[13];
  const float* dtw_b = (const float*)d_in[14];
  const float* dtb_b = (const float*)d_in[15];
  const float* Al_b  = (const float*)d_in[16];
  const float* D_b   = (const float*)d_in[17];
  const float* ow    = (const float*)d_in[18];
  float* out = (float*)d_out;

  float* ws = (float*)d_ws;
  float* xnT  = ws; ws += (size_t)16384 * 96;
  float* xz   = ws; ws += (size_t)2 * 384 * LSEQ;
  float* xc   = ws; ws += (size_t)4 * 192 * LSEQ;
  float* dt   = ws; ws += (size_t)4 * 192 * LSEQ;
  float* dbl  = ws; ws += (size_t)4 * 40 * LSEQ;
  float* Bo   = ws; ws += (size_t)4 * LSEQ * 16;
  float* Co   = ws; ws += (size_t)4 * LSEQ * 16;
  float* yf   = ws; ws += (size_t)2 * 192 * LSEQ;
  float* yb   = ws; ws += (size_t)2 * 192 * LSEQ;
  float* Pb   = ws; ws += (size_t)4 * NCH * 192 * 16;
  float* Hb   = ws; ws += (size_t)4 * NCH * 192 * 16;
  float* H0   = ws; ws += (size_t)4 * NCH * 192 * 16;
  float* xwT  = ws; ws += (size_t)2 * 192 * 64;
  float* inwT = ws; ws += (size_t)96 * 384;
  float* owT  = ws; ws += (size_t)192 * 96;

  k0_wt<<<dim3(64), dim3(256), 0, stream>>>(xw_f, xw_b, in_w, ow, xwT, inwT, owT);
  k1_serp_ln<<<dim3(256), dim3(256), 0, stream>>>(x, ln_g, ln_b, xnT);
  k2_inproj<<<dim3(256, 6), dim3(256), 0, stream>>>(xnT, inwT, xz);
  k3a_conv<<<dim3(32, 192, 2), dim3(256), 0, stream>>>(xz, cw_f, cb_f, cw_b, cb_b, xc);
  k3b1_xproj<<<dim3(512), dim3(256), 0, stream>>>(xc, xwT, dbl);
  k3b2_dtbc<<<dim3(128, 4), dim3(256), 0, stream>>>(dbl,
      dtw_f, dtb_f, dtw_b, dtb_b, dt, Bo, Co);
  k4_scanA<<<dim3(384, 2, 2), dim3(256), 0, stream>>>(dt, xc, Bo,
      Al_f, Al_b, Pb, Hb);
  k5_scanB<<<dim3(48), dim3(256), 0, stream>>>(Pb, Hb, H0);
  k6_scanC<<<dim3(384, 2, 2), dim3(256), 0, stream>>>(dt, xc, Bo, Co,
      xz, Al_f, Al_b, D_f, D_b, H0, yf, yb);
  k7_outproj<<<dim3(256, 2), dim3(256), 0, stream>>>(yf, yb, owT, out);
}